// Round 2
// baseline (776.531 us; speedup 1.0000x reference)
//
#include <hip/hip_runtime.h>
#include <math.h>

// Problem constants
#define NN 2048      // nodes per modality
#define TWO_N 4096   // total nodes
#define BB 4         // batch
#define CC 64        // input feature dim
#define HD 128       // hidden dim
#define CANDCAP 32   // max top-k candidates per row after margin filter

// Persistent-kernel geometry: 384 blocks x 512 threads (8 waves) = 3072 waves.
// 64KB LDS/block + <=128 VGPR (launch_bounds) => 2 blocks/CU co-resident,
// 384 blocks always simultaneously schedulable => spin barriers are safe.
#define NBLK 384
#define NTHR 512
#define NWAVES (NBLK * 8)

#define MAGIC0 0x13579BDF
#define MAGIC1 0x2468ACE1

typedef unsigned short u16;

// Barrier state (lives at start of workspace; workspace is poisoned between
// replays, so block 0 re-inits counters each run behind a magic handshake).
struct BarMem {
    int flag[16];          // [0],[1] = magic handshake words
    int sub[12][8][16];    // per-barrier, 8 cache-line-spread sub-counters
    int master[12][16];    // per-barrier master counter
};
#define BAR_ZERO_DWORDS (12 * 8 * 16 + 12 * 16)   // sub+master (not flags)

__device__ __forceinline__ void gbar(BarMem* B, int idx) {
    __syncthreads();
    if (threadIdx.x == 0) {
        int line = blockIdx.x & 7;
        int a = __hip_atomic_fetch_add(&B->sub[idx][line][0], 1,
                                       __ATOMIC_ACQ_REL, __HIP_MEMORY_SCOPE_AGENT);
        if (a == (NBLK / 8) - 1)
            __hip_atomic_fetch_add(&B->master[idx][0], 1,
                                   __ATOMIC_ACQ_REL, __HIP_MEMORY_SCOPE_AGENT);
        while (__hip_atomic_load(&B->master[idx][0],
                                 __ATOMIC_ACQUIRE, __HIP_MEMORY_SCOPE_AGENT) != 8)
            __builtin_amdgcn_s_sleep(2);
    }
    __syncthreads();
}

__device__ __forceinline__ u16 f2bf(float x) {   // RN-even f32 -> bf16
    unsigned u = __float_as_uint(x);
    u += 0x7FFFu + ((u >> 16) & 1u);
    return (u16)(u >> 16);
}

// ---------------------------------------------------------------------------
// The single persistent kernel. Phases separated by grid barriers:
//  P0 prep(W^T) + mean/norm + DV zero      |b0|
//  P1 sims (f32 compute, bf16 store, sym)  |b1|
//  P2 select+refine (f64-exact topK)       |b2|
//  P3 scan (CSR offsets, dvis)             |b3|
//  P4 fill CSR  +  layer1 edge (on raw x)  |b4|
//  P5 layer1 node (aggx, 64-dim)           |b5|
//  P6 z = relu(aggx @ W1^T)                |b6|
//  P7 y = z @ W2^T                         |b7|
//  P8 layer2 edge (on y, 128-dim)          |b8|
//  P9 layer2 node -> out
// ---------------------------------------------------------------------------
__global__ void __launch_bounds__(NTHR, 4)
k_uber(const float* __restrict__ f1, const float* __restrict__ f2,
       const float* __restrict__ W1, const float* __restrict__ W2,
       BarMem* __restrict__ bar,
       float* __restrict__ g32T, double* __restrict__ gR64,
       u16* __restrict__ simsbf,
       float* __restrict__ ybuf, float* __restrict__ zbuf,
       float* __restrict__ ubuf, float* __restrict__ aggx,
       float* __restrict__ W1T, float* __restrict__ W2T,
       float* __restrict__ dvisf,
       int* __restrict__ knn1, int* __restrict__ knn2,
       int* __restrict__ DV, int* __restrict__ offs,
       int* __restrict__ cursor, int* __restrict__ entries,
       float* __restrict__ out) {
    __shared__ __align__(16) char SMEM[65536];

    const int tid  = threadIdx.x;
    const int bid  = blockIdx.x;
    const int lane = tid & 63;
    const int wid  = tid >> 6;            // wave in block 0..7
    const int gwave = bid * 8 + wid;      // 0..3071
    const int team = tid >> 8;            // 256-thread team 0..1
    const int tid2 = tid & 255;

    // ---- init handshake (barrier state is poisoned between replays) ----
    if (bid == 0) {
        int* bz = &bar->sub[0][0][0];
        for (int i = tid; i < BAR_ZERO_DWORDS; i += NTHR) bz[i] = 0;
        __syncthreads();
        if (tid == 0) {
            __hip_atomic_store(&bar->flag[0], MAGIC0, __ATOMIC_RELEASE, __HIP_MEMORY_SCOPE_AGENT);
            __hip_atomic_store(&bar->flag[1], MAGIC1, __ATOMIC_RELEASE, __HIP_MEMORY_SCOPE_AGENT);
        }
    } else {
        if (tid == 0) {
            while (__hip_atomic_load(&bar->flag[0], __ATOMIC_ACQUIRE, __HIP_MEMORY_SCOPE_AGENT) != MAGIC0 ||
                   __hip_atomic_load(&bar->flag[1], __ATOMIC_ACQUIRE, __HIP_MEMORY_SCOPE_AGENT) != MAGIC1)
                __builtin_amdgcn_s_sleep(2);
        }
        __syncthreads();
    }

    // ======================= P0: prep + mean/norm + DV=0 ====================
    {
        int gid = bid * NTHR + tid;
        if (gid < HD * CC) {              // W1T[k][c]
            int c = gid >> 6, k = gid & 63;
            W1T[(size_t)k * HD + c] = W1[gid];
        }
        if (gid < HD * HD) {              // W2T[k][c]
            int c = gid >> 7, k = gid & 127;
            W2T[(size_t)k * HD + c] = W2[gid];
        }
        if (gid < TWO_N) DV[gid] = 0;

        for (int rowt = gwave; rowt < TWO_N; rowt += NWAVES) {
            int m = rowt >> 11, n = rowt & 2047;
            const float* f = m ? f2 : f1;
            double s = 0.0;
            for (int b = 0; b < BB; ++b)
                s += (double)f[((size_t)(b * NN) + n) * CC + lane];
            double mean = s * 0.25;
            double sq = mean * mean;
            for (int d = 32; d >= 1; d >>= 1) sq += __shfl_xor(sq, d);
            double norm = sqrt(sq);
            if (norm < 1e-12) norm = 1e-12;
            double gg = mean / norm;
            g32T[((size_t)m * CC + lane) * NN + n] = (float)gg;
            gR64[((size_t)m * NN + n) * CC + lane] = gg;
        }
    }
    gbar(bar, 0);

    // ======================= P1: sims (bf16, symmetric) =====================
    // 1056 upper-tri 64x64 tiles (2 mods x 528) over 768 teams, 2 uniform iters.
    {
        for (int itr = 0; itr < 2; ++itr) {
            int tile = bid * 2 + team + itr * (NBLK * 2);
            bool act = tile < 1056;
            int m = 0, bi = 0, bj = 0;
            if (act) {
                m = tile >= 528 ? 1 : 0;
                int r = tile - m * 528;
                while (r >= 32 - bi) { r -= 32 - bi; ++bi; }
                bj = bi + r;
            }
            float* As = (float*)(SMEM + (size_t)team * 32768);   // [64][64]
            float* Bs = As + 4096;                               // [64][64]
            int i0 = bi * 64, j0 = bj * 64;
            const float* g = g32T + (size_t)m * CC * NN;
            if (act) {
                #pragma unroll
                for (int q = 0; q < 16; ++q) {
                    int idx = q * 256 + tid2;
                    int k = idx >> 6, rr = idx & 63;
                    As[k * 64 + rr] = g[(size_t)k * NN + i0 + rr];
                    Bs[k * 64 + rr] = g[(size_t)k * NN + j0 + rr];
                }
            }
            __syncthreads();
            float acc[4][4] = {{0.f}};
            int tr = tid2 >> 4, tc = tid2 & 15;
            if (act) {
                #pragma unroll
                for (int k = 0; k < CC; ++k) {
                    float4 a = *((const float4*)&As[k * 64 + (tr << 2)]);
                    float4 b = *((const float4*)&Bs[k * 64 + (tc << 2)]);
                    acc[0][0] += a.x * b.x; acc[0][1] += a.x * b.y; acc[0][2] += a.x * b.z; acc[0][3] += a.x * b.w;
                    acc[1][0] += a.y * b.x; acc[1][1] += a.y * b.y; acc[1][2] += a.y * b.z; acc[1][3] += a.y * b.w;
                    acc[2][0] += a.z * b.x; acc[2][1] += a.z * b.y; acc[2][2] += a.z * b.z; acc[2][3] += a.z * b.w;
                    acc[3][0] += a.w * b.x; acc[3][1] += a.w * b.y; acc[3][2] += a.w * b.z; acc[3][3] += a.w * b.w;
                }
            }
            __syncthreads();                 // As free -> reuse as bf16 bounce
            u16* Cs = (u16*)As;              // [64][66] stride 66: conflict-free
            u16* srow = simsbf + (size_t)m * NN * NN;
            if (act) {
                #pragma unroll
                for (int x = 0; x < 4; ++x) {
                    ushort4 vd;
                    vd.x = f2bf(acc[x][0]); vd.y = f2bf(acc[x][1]);
                    vd.z = f2bf(acc[x][2]); vd.w = f2bf(acc[x][3]);
                    *((ushort4*)&srow[(size_t)(i0 + (tr << 2) + x) * NN + j0 + (tc << 2)]) = vd;
                    int cr = ((tr << 2) + x) * 66 + (tc << 2);
                    Cs[cr + 0] = vd.x; Cs[cr + 1] = vd.y;
                    Cs[cr + 2] = vd.z; Cs[cr + 3] = vd.w;
                }
            }
            __syncthreads();
            if (act) {
                #pragma unroll
                for (int q = 0; q < 4; ++q) {
                    int idx = q * 256 + tid2;
                    int cc = idx >> 4, rr4 = (idx & 15) << 2;
                    ushort4 vd;
                    vd.x = Cs[(rr4 + 0) * 66 + cc];
                    vd.y = Cs[(rr4 + 1) * 66 + cc];
                    vd.z = Cs[(rr4 + 2) * 66 + cc];
                    vd.w = Cs[(rr4 + 3) * 66 + cc];
                    *((ushort4*)&srow[(size_t)(j0 + cc) * NN + i0 + rr4]) = vd;
                }
            }
            __syncthreads();
        }
    }
    gbar(bar, 1);

    // ======================= P2: select + f64 refine ========================
    // Per-wave, barrier-free (per-wave LDS slices + wave fences). Margin 6e-3
    // covers bf16 storage (<=2.05e-3 each side) + f32 compute err + window.
    {
        int* candL = (int*)(SMEM + (size_t)wid * 384);
        double* dotsL = (double*)(SMEM + (size_t)wid * 384 + 128);
        for (int row = gwave; row < TWO_N; row += NWAVES) {
            int m = row >> 11, i = row & 2047;
            int K = m ? 13 : 19;
            const u16* s = simsbf + (size_t)m * NN * NN + (size_t)i * NN;
            float sv[32];
            #pragma unroll
            for (int q = 0; q < 4; ++q) {
                uint4 w = *((const uint4*)(s + q * 512 + (lane << 3)));
                sv[q*8+0] = __uint_as_float(w.x << 16);
                sv[q*8+1] = __uint_as_float(w.x & 0xFFFF0000u);
                sv[q*8+2] = __uint_as_float(w.y << 16);
                sv[q*8+3] = __uint_as_float(w.y & 0xFFFF0000u);
                sv[q*8+4] = __uint_as_float(w.z << 16);
                sv[q*8+5] = __uint_as_float(w.z & 0xFFFF0000u);
                sv[q*8+6] = __uint_as_float(w.w << 16);
                sv[q*8+7] = __uint_as_float(w.w & 0xFFFF0000u);
            }
            float lo = -1.01f, hi = 1.01f;
            for (int it = 0; it < 12; ++it) {
                float t = 0.5f * (lo + hi);
                int c = 0;
                #pragma unroll
                for (int r = 0; r < 32; ++r)
                    c += __popcll(__ballot(sv[r] >= t));
                if (c >= K) lo = t; else hi = t;   // wave-uniform
            }
            float thr = lo - 6e-3f;
            unsigned long long ltmask = (lane == 0) ? 0ull : ((~0ull) >> (64 - lane));
            int base = 0;
            #pragma unroll
            for (int r = 0; r < 32; ++r) {
                int j = ((r >> 3) << 9) + (lane << 3) + (r & 7);
                bool p = sv[r] >= thr;
                unsigned long long mk = __ballot(p);
                int ofs = base + __popcll(mk & ltmask);
                if (p && ofs < CANDCAP) candL[ofs] = j;
                base += __popcll(mk);
            }
            int cnt = (base < CANDCAP) ? base : CANDCAP;
            __threadfence_block();
            const double* gm = gR64 + (size_t)m * NN * CC;
            double qc = gm[(size_t)i * CC + lane];
            int t4 = 0;
            for (; t4 + 3 < cnt; t4 += 4) {       // 4 independent reduce chains
                int j0c = candL[t4 + 0], j1c = candL[t4 + 1];
                int j2c = candL[t4 + 2], j3c = candL[t4 + 3];
                double p0 = qc * gm[(size_t)j0c * CC + lane];
                double p1 = qc * gm[(size_t)j1c * CC + lane];
                double p2 = qc * gm[(size_t)j2c * CC + lane];
                double p3 = qc * gm[(size_t)j3c * CC + lane];
                #pragma unroll
                for (int d = 32; d >= 1; d >>= 1) {
                    p0 += __shfl_xor(p0, d); p1 += __shfl_xor(p1, d);
                    p2 += __shfl_xor(p2, d); p3 += __shfl_xor(p3, d);
                }
                if (lane == 0) {
                    dotsL[t4 + 0] = p0; dotsL[t4 + 1] = p1;
                    dotsL[t4 + 2] = p2; dotsL[t4 + 3] = p3;
                }
            }
            for (; t4 < cnt; ++t4) {
                int j = candL[t4];
                double p = qc * gm[(size_t)j * CC + lane];
                #pragma unroll
                for (int d = 32; d >= 1; d >>= 1) p += __shfl_xor(p, d);
                if (lane == 0) dotsL[t4] = p;
            }
            __threadfence_block();
            int* knn = m ? knn2 : knn1;
            if (lane < cnt) {
                double vt = dotsL[lane]; int jt = candL[lane];
                int rank = 0;
                for (int s2 = 0; s2 < cnt; ++s2) {
                    double vs = dotsL[s2]; int js = candL[s2];
                    if (vs > vt || (vs == vt && js < jt)) ++rank;
                }
                if (rank < K) {
                    knn[(size_t)i * K + rank] = jt;
                    int w = (rank < (m ? 5 : 7)) ? 2 : 1;
                    atomicAdd(&DV[m ? NN + jt : jt], w);
                }
            }
            __threadfence_block();
        }
    }
    gbar(bar, 2);

    // ======================= P3: scan (1 wave) ==============================
    if (bid == 0 && tid < 64) {
        int ln = tid;
        int base = ln * 64;
        int s = 0;
        for (int q = 0; q < 64; ++q) s += DV[base + q];
        int x = s;
        for (int d = 1; d < 64; d <<= 1) {
            int y = __shfl_up(x, d);
            if (ln >= d) x += y;
        }
        int run = x - s;
        for (int q = 0; q < 64; ++q) {
            int v = base + q;
            offs[v] = run; cursor[v] = run;
            dvisf[v] = (float)(1.0 / sqrt((double)(DV[v] + 1)));
            run += DV[v];
        }
        if (ln == 63) offs[TWO_N] = run;
    }
    gbar(bar, 3);

    // ======================= P4: fill CSR + layer1 edge =====================
    {
        int gid = bid * NTHR + tid;
        const int M1 = NN * 19, M2 = NN * 13;
        if (gid < M1) {
            int i = gid / 19, t = gid % 19;
            int v = knn1[gid];
            int p = atomicAdd(&cursor[v], 1); entries[p] = NN + i;
            if (t < 7) { int p2 = atomicAdd(&cursor[v], 1); entries[p2] = i; }
        } else if (gid < M1 + M2) {
            int id2 = gid - M1;
            int i = id2 / 13, t = id2 % 13;
            int v = NN + knn2[id2];
            int p = atomicAdd(&cursor[v], 1); entries[p] = 3 * NN + i;
            if (t < 5) { int p2 = atomicAdd(&cursor[v], 1); entries[p2] = 2 * NN + i; }
        }

        // layer1 edge on raw x (64-dim), paired edges, shfl-broadcast members
        const float4* x1 = (const float4*)f1;
        const float4* x2 = (const float4*)f2;
        float4* u4 = (float4*)ubuf;
        for (int pt = gwave; pt < TWO_N; pt += NWAVES) {
            int ff = lane & 15, b = lane >> 4;
            if (pt < NN) {
                int mv = 0; float wv = 0.f;
                if (lane < 19) { mv = knn1[(size_t)pt * 19 + lane]; wv = dvisf[mv]; }
                float ax = 0.f, ay = 0.f, az = 0.f, aw = 0.f;
                #pragma unroll
                for (int q = 0; q < 7; ++q) {
                    int mq = __shfl(mv, q); float wq = __shfl(wv, q);
                    float4 val = x1[((size_t)(b * NN) + mq) * 16 + ff];
                    ax += val.x * wq; ay += val.y * wq; az += val.z * wq; aw += val.w * wq;
                }
                u4[(size_t)pt * 64 + lane] =
                    make_float4(ax * (1.f/49.f), ay * (1.f/49.f), az * (1.f/49.f), aw * (1.f/49.f));
                #pragma unroll
                for (int q = 7; q < 19; ++q) {
                    int mq = __shfl(mv, q); float wq = __shfl(wv, q);
                    float4 val = x1[((size_t)(b * NN) + mq) * 16 + ff];
                    ax += val.x * wq; ay += val.y * wq; az += val.z * wq; aw += val.w * wq;
                }
                u4[(size_t)(NN + pt) * 64 + lane] =
                    make_float4(ax * (1.f/361.f), ay * (1.f/361.f), az * (1.f/361.f), aw * (1.f/361.f));
            } else {
                int i = pt - NN;
                int mv = 0; float wv = 0.f;
                if (lane < 13) { mv = knn2[(size_t)i * 13 + lane]; wv = dvisf[NN + mv]; }
                float ax = 0.f, ay = 0.f, az = 0.f, aw = 0.f;
                #pragma unroll
                for (int q = 0; q < 5; ++q) {
                    int mq = __shfl(mv, q); float wq = __shfl(wv, q);
                    float4 val = x2[((size_t)(b * NN) + mq) * 16 + ff];
                    ax += val.x * wq; ay += val.y * wq; az += val.z * wq; aw += val.w * wq;
                }
                u4[(size_t)(2 * NN + i) * 64 + lane] =
                    make_float4(ax * (1.f/25.f), ay * (1.f/25.f), az * (1.f/25.f), aw * (1.f/25.f));
                #pragma unroll
                for (int q = 5; q < 13; ++q) {
                    int mq = __shfl(mv, q); float wq = __shfl(wv, q);
                    float4 val = x2[((size_t)(b * NN) + mq) * 16 + ff];
                    ax += val.x * wq; ay += val.y * wq; az += val.z * wq; aw += val.w * wq;
                }
                u4[(size_t)(3 * NN + i) * 64 + lane] =
                    make_float4(ax * (1.f/169.f), ay * (1.f/169.f), az * (1.f/169.f), aw * (1.f/169.f));
            }
        }
    }
    gbar(bar, 4);

    // ======================= P5: layer1 node -> aggx ========================
    {
        const float4* u4 = (const float4*)ubuf;
        const float4* x1 = (const float4*)f1;
        const float4* x2 = (const float4*)f2;
        float4* aggx4 = (float4*)aggx;
        for (int v = gwave; v < TWO_N; v += NWAVES) {
            int ff = lane & 15, b = lane >> 4;
            int s = offs[v], e_end = offs[v + 1];
            float a0x=0,a0y=0,a0z=0,a0w=0, a1x=0,a1y=0,a1z=0,a1w=0;
            float a2x=0,a2y=0,a2z=0,a2w=0, a3x=0,a3y=0,a3z=0,a3w=0;
            int p = s;
            for (; p + 3 < e_end; p += 4) {
                int e0 = entries[p], e1 = entries[p+1], e2 = entries[p+2], e3 = entries[p+3];
                float4 v0 = u4[(size_t)e0 * 64 + lane];
                float4 v1 = u4[(size_t)e1 * 64 + lane];
                float4 v2 = u4[(size_t)e2 * 64 + lane];
                float4 v3 = u4[(size_t)e3 * 64 + lane];
                a0x+=v0.x;a0y+=v0.y;a0z+=v0.z;a0w+=v0.w;
                a1x+=v1.x;a1y+=v1.y;a1z+=v1.z;a1w+=v1.w;
                a2x+=v2.x;a2y+=v2.y;a2z+=v2.z;a2w+=v2.w;
                a3x+=v3.x;a3y+=v3.y;a3z+=v3.z;a3w+=v3.w;
            }
            for (; p < e_end; ++p) {
                float4 v0 = u4[(size_t)entries[p] * 64 + lane];
                a0x+=v0.x;a0y+=v0.y;a0z+=v0.z;a0w+=v0.w;
            }
            float ax = (a0x+a1x)+(a2x+a3x);
            float ay = (a0y+a1y)+(a2y+a3y);
            float az = (a0z+a1z)+(a2z+a3z);
            float aw = (a0w+a1w)+(a2w+a3w);
            int partner = (v < NN) ? v + NN : v - NN;
            float w0 = dvisf[v], w1 = dvisf[partner];
            float4 xv = (v < NN) ? x1[((size_t)(b*NN) + v) * 16 + ff]
                                 : x2[((size_t)(b*NN) + (v - NN)) * 16 + ff];
            float4 xp = (partner < NN) ? x1[((size_t)(b*NN) + partner) * 16 + ff]
                                       : x2[((size_t)(b*NN) + (partner - NN)) * 16 + ff];
            ax += 0.25f * (xv.x * w0 + xp.x * w1);
            ay += 0.25f * (xv.y * w0 + xp.y * w1);
            az += 0.25f * (xv.z * w0 + xp.z * w1);
            aw += 0.25f * (xv.w * w0 + xp.w * w1);
            ax *= w0; ay *= w0; az *= w0; aw *= w0;
            aggx4[(size_t)v * 64 + lane] = make_float4(ax, ay, az, aw);
        }
    }
    gbar(bar, 5);

    // ======================= P6: z = relu(aggx @ W1^T) ======================
    {
        float* wT = (float*)SMEM;                              // [64][132]
        float* xT = ((float*)(SMEM + 33792)) + team * 2112;    // [64][33]
        #pragma unroll
        for (int p = 0; p < 16; ++p) {
            int idx = p * NTHR + tid;                          // 8192 elems
            wT[(idx >> 7) * 132 + (idx & 127)] = W1T[idx];
        }
        int gteam = bid * 2 + team;
        bool act = gteam < (BB * TWO_N) / 32;                  // 512 tasks
        int g0 = gteam * 32;
        if (act) {
            #pragma unroll
            for (int q = 0; q < 8; ++q) {
                int idx = q * 256 + tid2;
                int row = idx >> 6, k = idx & 63;
                xT[k * 33 + row] = aggx[(size_t)(g0 + row) * CC + k];
            }
        }
        __syncthreads();
        if (act) {
            int tr = tid2 >> 5, tc = tid2 & 31;
            int r0 = tr * 4, c0 = tc * 4;
            float acc[4][4] = {{0.f}};
            #pragma unroll
            for (int k = 0; k < CC; ++k) {
                float xr0 = xT[k*33 + r0+0], xr1 = xT[k*33 + r0+1];
                float xr2 = xT[k*33 + r0+2], xr3 = xT[k*33 + r0+3];
                float4 w = *((const float4*)&wT[k * 132 + c0]);
                acc[0][0]+=xr0*w.x; acc[0][1]+=xr0*w.y; acc[0][2]+=xr0*w.z; acc[0][3]+=xr0*w.w;
                acc[1][0]+=xr1*w.x; acc[1][1]+=xr1*w.y; acc[1][2]+=xr1*w.z; acc[1][3]+=xr1*w.w;
                acc[2][0]+=xr2*w.x; acc[2][1]+=xr2*w.y; acc[2][2]+=xr2*w.z; acc[2][3]+=xr2*w.w;
                acc[3][0]+=xr3*w.x; acc[3][1]+=xr3*w.y; acc[3][2]+=xr3*w.z; acc[3][3]+=xr3*w.w;
            }
            #pragma unroll
            for (int i = 0; i < 4; ++i) {
                float4 v = make_float4(fmaxf(acc[i][0],0.f), fmaxf(acc[i][1],0.f),
                                       fmaxf(acc[i][2],0.f), fmaxf(acc[i][3],0.f));
                *((float4*)&zbuf[(size_t)(g0 + r0 + i) * HD + c0]) = v;
            }
        }
    }
    gbar(bar, 6);

    // ======================= P7: y = z @ W2^T ===============================
    {
        float* wT = (float*)SMEM;                              // [64][132]
        float* zT = ((float*)(SMEM + 33792)) + team * 2112;    // [64][33]
        int gteam = bid * 2 + team;
        bool act = gteam < (BB * TWO_N) / 32;
        int g0 = gteam * 32;
        int tr = tid2 >> 5, tc = tid2 & 31;
        int r0 = tr * 4, c0 = tc * 4;
        float acc[4][4] = {{0.f}};
        for (int kc = 0; kc < 2; ++kc) {
            __syncthreads();
            #pragma unroll
            for (int p = 0; p < 16; ++p) {
                int idx = p * NTHR + tid;
                int k = idx >> 7, c = idx & 127;
                wT[k * 132 + c] = W2T[(size_t)(kc * 64 + k) * HD + c];
            }
            if (act) {
                #pragma unroll
                for (int q = 0; q < 8; ++q) {
                    int idx = q * 256 + tid2;
                    int row = idx >> 6, k = idx & 63;
                    zT[k * 33 + row] = zbuf[(size_t)(g0 + row) * HD + kc * 64 + k];
                }
            }
            __syncthreads();
            if (act) {
                #pragma unroll
                for (int k = 0; k < 64; ++k) {
                    float zr0 = zT[k*33 + r0+0], zr1 = zT[k*33 + r0+1];
                    float zr2 = zT[k*33 + r0+2], zr3 = zT[k*33 + r0+3];
                    float4 w = *((const float4*)&wT[k * 132 + c0]);
                    acc[0][0]+=zr0*w.x; acc[0][1]+=zr0*w.y; acc[0][2]+=zr0*w.z; acc[0][3]+=zr0*w.w;
                    acc[1][0]+=zr1*w.x; acc[1][1]+=zr1*w.y; acc[1][2]+=zr1*w.z; acc[1][3]+=zr1*w.w;
                    acc[2][0]+=zr2*w.x; acc[2][1]+=zr2*w.y; acc[2][2]+=zr2*w.z; acc[2][3]+=zr2*w.w;
                    acc[3][0]+=zr3*w.x; acc[3][1]+=zr3*w.y; acc[3][2]+=zr3*w.z; acc[3][3]+=zr3*w.w;
                }
            }
        }
        if (act) {
            #pragma unroll
            for (int i = 0; i < 4; ++i) {
                float4 v = make_float4(acc[i][0], acc[i][1], acc[i][2], acc[i][3]);
                *((float4*)&ybuf[(size_t)(g0 + r0 + i) * HD + c0]) = v;
            }
        }
    }
    gbar(bar, 7);

    // ======================= P8: layer2 edge (on y) =========================
    {
        const float4* y4 = (const float4*)ybuf;
        float4* u4 = (float4*)ubuf;
        int wteam = wid >> 1, wsub = wid & 1;
        int gt2 = bid * 4 + wteam;                 // 0..1535 (2-wave teams)
        for (int pt = gt2; pt < TWO_N; pt += NBLK * 4) {
            int ff = lane & 31;
            int b = wsub * 2 + (lane >> 5);
            int bo = b * 32 + ff;
            if (pt < NN) {
                int mv = 0; float wv = 0.f;
                if (lane < 19) { mv = knn1[(size_t)pt * 19 + lane]; wv = dvisf[mv]; }
                float ax=0,ay=0,az=0,aw=0;
                #pragma unroll
                for (int q = 0; q < 7; ++q) {
                    int mq = __shfl(mv, q); float wq = __shfl(wv, q);
                    float4 val = y4[(size_t)mq * 128 + bo];
                    ax += val.x*wq; ay += val.y*wq; az += val.z*wq; aw += val.w*wq;
                }
                u4[(size_t)pt * 128 + bo] =
                    make_float4(ax*(1.f/49.f), ay*(1.f/49.f), az*(1.f/49.f), aw*(1.f/49.f));
                #pragma unroll
                for (int q = 7; q < 19; ++q) {
                    int mq = __shfl(mv, q); float wq = __shfl(wv, q);
                    float4 val = y4[(size_t)mq * 128 + bo];
                    ax += val.x*wq; ay += val.y*wq; az += val.z*wq; aw += val.w*wq;
                }
                u4[(size_t)(NN + pt) * 128 + bo] =
                    make_float4(ax*(1.f/361.f), ay*(1.f/361.f), az*(1.f/361.f), aw*(1.f/361.f));
            } else {
                int i = pt - NN;
                int mv = 0; float wv = 0.f;
                if (lane < 13) { mv = NN + knn2[(size_t)i * 13 + lane]; wv = dvisf[mv]; }
                float ax=0,ay=0,az=0,aw=0;
                #pragma unroll
                for (int q = 0; q < 5; ++q) {
                    int mq = __shfl(mv, q); float wq = __shfl(wv, q);
                    float4 val = y4[(size_t)mq * 128 + bo];
                    ax += val.x*wq; ay += val.y*wq; az += val.z*wq; aw += val.w*wq;
                }
                u4[(size_t)(2 * NN + i) * 128 + bo] =
                    make_float4(ax*(1.f/25.f), ay*(1.f/25.f), az*(1.f/25.f), aw*(1.f/25.f));
                #pragma unroll
                for (int q = 5; q < 13; ++q) {
                    int mq = __shfl(mv, q); float wq = __shfl(wv, q);
                    float4 val = y4[(size_t)mq * 128 + bo];
                    ax += val.x*wq; ay += val.y*wq; az += val.z*wq; aw += val.w*wq;
                }
                u4[(size_t)(3 * NN + i) * 128 + bo] =
                    make_float4(ax*(1.f/169.f), ay*(1.f/169.f), az*(1.f/169.f), aw*(1.f/169.f));
            }
        }
    }
    gbar(bar, 8);

    // ======================= P9: layer2 node -> out =========================
    {
        const float4* u4 = (const float4*)ubuf;
        const float4* y4 = (const float4*)ybuf;
        float4* outp4 = (float4*)out;
        int wteam = wid >> 1, wsub = wid & 1;
        int gt2 = bid * 4 + wteam;
        for (int v = gt2; v < TWO_N; v += NBLK * 4) {
            int ff = lane & 31;
            int b = wsub * 2 + (lane >> 5);
            int bo = b * 32 + ff;
            int s = offs[v], e_end = offs[v + 1];
            float a0x=0,a0y=0,a0z=0,a0w=0, a1x=0,a1y=0,a1z=0,a1w=0;
            float a2x=0,a2y=0,a2z=0,a2w=0, a3x=0,a3y=0,a3z=0,a3w=0;
            int p = s;
            for (; p + 3 < e_end; p += 4) {
                int e0 = entries[p], e1 = entries[p+1], e2 = entries[p+2], e3 = entries[p+3];
                float4 v0 = u4[(size_t)e0 * 128 + bo];
                float4 v1 = u4[(size_t)e1 * 128 + bo];
                float4 v2 = u4[(size_t)e2 * 128 + bo];
                float4 v3 = u4[(size_t)e3 * 128 + bo];
                a0x+=v0.x;a0y+=v0.y;a0z+=v0.z;a0w+=v0.w;
                a1x+=v1.x;a1y+=v1.y;a1z+=v1.z;a1w+=v1.w;
                a2x+=v2.x;a2y+=v2.y;a2z+=v2.z;a2w+=v2.w;
                a3x+=v3.x;a3y+=v3.y;a3z+=v3.z;a3w+=v3.w;
            }
            for (; p < e_end; ++p) {
                float4 v0 = u4[(size_t)entries[p] * 128 + bo];
                a0x+=v0.x;a0y+=v0.y;a0z+=v0.z;a0w+=v0.w;
            }
            float ax = (a0x+a1x)+(a2x+a3x);
            float ay = (a0y+a1y)+(a2y+a3y);
            float az = (a0z+a1z)+(a2z+a3z);
            float aw = (a0w+a1w)+(a2w+a3w);
            int partner = (v < NN) ? v + NN : v - NN;
            float w0 = dvisf[v], w1 = dvisf[partner];
            float4 yv = y4[(size_t)v * 128 + bo];
            float4 yp = y4[(size_t)partner * 128 + bo];
            ax += 0.25f * (yv.x * w0 + yp.x * w1);
            ay += 0.25f * (yv.y * w0 + yp.y * w1);
            az += 0.25f * (yv.z * w0 + yp.z * w1);
            aw += 0.25f * (yv.w * w0 + yp.w * w1);
            ax *= w0; ay *= w0; az *= w0; aw *= w0;
            float4 res = make_float4(fmaxf(ax,0.f), fmaxf(ay,0.f),
                                     fmaxf(az,0.f), fmaxf(aw,0.f));
            size_t o;
            if (v < NN) o = ((size_t)(b * NN + v)) * 32 + ff;
            else        o = (size_t)BB * NN * 32 + ((size_t)(b * NN + (v - NN))) * 32 + ff;
            outp4[o] = res;
        }
    }

    // close the handshake so a replay without re-poisoning can't see stale magic
    if (bid == 0 && tid == 0) {
        __hip_atomic_store(&bar->flag[0], 0, __ATOMIC_RELEASE, __HIP_MEMORY_SCOPE_AGENT);
        __hip_atomic_store(&bar->flag[1], 0, __ATOMIC_RELEASE, __HIP_MEMORY_SCOPE_AGENT);
    }
}

// ---------------------------------------------------------------------------
extern "C" void kernel_launch(void* const* d_in, const int* in_sizes, int n_in,
                              void* d_out, int out_size, void* d_ws, size_t ws_size,
                              hipStream_t stream) {
    const float* f1 = (const float*)d_in[0];
    const float* f2 = (const float*)d_in[1];
    const float* W1 = (const float*)d_in[2];
    const float* W2 = (const float*)d_in[3];
    float* out = (float*)d_out;

    char* ws = (char*)d_ws;
    size_t off = 0;
    auto alloc = [&](size_t bytes) -> void* {
        void* p = ws + off;
        off = (off + bytes + 255) & ~(size_t)255;
        return p;
    };
    BarMem* bar    = (BarMem*)alloc(sizeof(BarMem));                  // ~7 KB
    float*  g32T   = (float*)alloc((size_t)2 * CC * NN * 4);          // 1 MB
    double* gR64   = (double*)alloc((size_t)2 * NN * CC * 8);         // 2 MB
    u16*    simsbf = (u16*)alloc((size_t)2 * NN * NN * 2);            // 16 MB
    float*  ybuf   = (float*)alloc((size_t)BB * TWO_N * HD * 4);      // 8 MB
    float*  zbuf   = (float*)alloc((size_t)BB * TWO_N * HD * 4);      // 8 MB
    float*  ubuf   = (float*)alloc((size_t)BB * 4 * NN * HD * 4);     // 16 MB
    float*  aggx   = (float*)alloc((size_t)BB * TWO_N * CC * 4);      // 4 MB
    float*  W1T    = (float*)alloc((size_t)CC * HD * 4);
    float*  W2T    = (float*)alloc((size_t)HD * HD * 4);
    float*  dvisf  = (float*)alloc((size_t)TWO_N * 4);
    int*    knn1   = (int*)alloc((size_t)NN * 19 * 4);
    int*    knn2   = (int*)alloc((size_t)NN * 13 * 4);
    int*    DV     = (int*)alloc((size_t)TWO_N * 4);
    int*    offs   = (int*)alloc((size_t)(TWO_N + 1) * 4);
    int*    cursor = (int*)alloc((size_t)TWO_N * 4);
    int*    entries= (int*)alloc((size_t)(NN * 26 + NN * 18) * 4);

    k_uber<<<dim3(NBLK), dim3(NTHR), 0, stream>>>(
        f1, f2, W1, W2, bar, g32T, gR64, simsbf, ybuf, zbuf, ubuf, aggx,
        W1T, W2T, dvisf, knn1, knn2, DV, offs, cursor, entries, out);
}

// Round 3
// 344.463 us; speedup vs baseline: 2.2543x; 2.2543x over previous
//
#include <hip/hip_runtime.h>
#include <math.h>

// Problem constants
#define NN 2048      // nodes per modality
#define TWO_N 4096   // total nodes
#define BB 4         // batch
#define CC 64        // input feature dim
#define HD 128       // hidden dim
#define CANDCAP 32   // max top-k candidates per row after margin filter

// Persistent-kernel geometry: 384 blocks x 512 threads (8 waves) = 3072 waves.
// 64KB LDS/block + <=128 VGPR => 2 blocks/CU co-resident, 384 <= 512 slots.
#define NBLK 384
#define NTHR 512
#define NWAVES (NBLK * 8)

#define MAGIC0 0x13579BDF
#define MAGIC1 0x2468ACE1

typedef unsigned short u16;

// Barrier state (start of workspace; poisoned between replays, so block 0
// re-inits counters each run behind a magic handshake).
struct BarMem {
    int flag[16];          // [0],[1] = magic handshake words
    int sub[12][8][16];    // per-barrier, 8 cache-line-spread sub-counters
    int master[12][16];    // per-barrier master counter
};
#define BAR_ZERO_DWORDS (12 * 8 * 16 + 12 * 16)   // sub+master (not flags)

// Cache-benign grid barrier: RELAXED spin (no per-iteration buffer_inv),
// single ACQUIRE load after exit; release folded into the one arrival add.
__device__ __forceinline__ void gbar(BarMem* B, int idx) {
    __syncthreads();
    if (threadIdx.x == 0) {
        int line = blockIdx.x & 7;
        int a = __hip_atomic_fetch_add(&B->sub[idx][line][0], 1,
                                       __ATOMIC_ACQ_REL, __HIP_MEMORY_SCOPE_AGENT);
        if (a == (NBLK / 8) - 1)
            __hip_atomic_fetch_add(&B->master[idx][0], 1,
                                   __ATOMIC_ACQ_REL, __HIP_MEMORY_SCOPE_AGENT);
        while (__hip_atomic_load(&B->master[idx][0],
                                 __ATOMIC_RELAXED, __HIP_MEMORY_SCOPE_AGENT) != 8)
            __builtin_amdgcn_s_sleep(8);
        (void)__hip_atomic_load(&B->master[idx][0],
                                __ATOMIC_ACQUIRE, __HIP_MEMORY_SCOPE_AGENT);
    }
    __syncthreads();
}

__device__ __forceinline__ u16 f2bf(float x) {   // RN-even f32 -> bf16
    unsigned u = __float_as_uint(x);
    u += 0x7FFFu + ((u >> 16) & 1u);
    return (u16)(u >> 16);
}

// ---------------------------------------------------------------------------
// Phases / barriers:
//  P0 prep(W^T) + mean/norm + DV zero      |b0|
//  P1 sims (f32 compute, bf16 store, sym)  |b1|
//  P2 select+refine (f64-exact topK)       |b2|
//  P3 scan (CSR offsets, dvis)             |b3|
//  P4 fill CSR  +  layer1 edge (on raw x)  |b4|
//  P5 node1 -> LDS -> gemm1 -> z -> gemm2  |b5|   (team-local z, no grid sync)
//  P6 layer2 edge (on y, 128-dim)          |b6|
//  P7 layer2 node -> out
// ---------------------------------------------------------------------------
__global__ void __launch_bounds__(NTHR, 4)
k_uber(const float* __restrict__ f1, const float* __restrict__ f2,
       const float* __restrict__ W1, const float* __restrict__ W2,
       BarMem* __restrict__ bar,
       float* __restrict__ g32T, double* __restrict__ gR64,
       u16* __restrict__ simsbf,
       float* __restrict__ ybuf, float* __restrict__ zbuf,
       float* __restrict__ ubuf,
       float* __restrict__ W1T, float* __restrict__ W2T,
       float* __restrict__ dvisf,
       int* __restrict__ knn1, int* __restrict__ knn2,
       int* __restrict__ DV, int* __restrict__ offs,
       int* __restrict__ cursor, int* __restrict__ entries,
       float* __restrict__ out) {
    __shared__ __align__(16) char SMEM[65536];

    const int tid  = threadIdx.x;
    const int bid  = blockIdx.x;
    const int lane = tid & 63;
    const int wid  = tid >> 6;            // wave in block 0..7
    const int gwave = bid * 8 + wid;      // 0..3071
    const int team = tid >> 8;            // 256-thread team 0..1
    const int tid2 = tid & 255;

    // ---- init handshake (barrier state is poisoned between replays) ----
    if (bid == 0) {
        int* bz = &bar->sub[0][0][0];
        for (int i = tid; i < BAR_ZERO_DWORDS; i += NTHR) bz[i] = 0;
        __syncthreads();
        if (tid == 0) {
            __hip_atomic_store(&bar->flag[0], MAGIC0, __ATOMIC_RELEASE, __HIP_MEMORY_SCOPE_AGENT);
            __hip_atomic_store(&bar->flag[1], MAGIC1, __ATOMIC_RELEASE, __HIP_MEMORY_SCOPE_AGENT);
        }
    } else {
        if (tid == 0) {
            while (__hip_atomic_load(&bar->flag[0], __ATOMIC_RELAXED, __HIP_MEMORY_SCOPE_AGENT) != MAGIC0 ||
                   __hip_atomic_load(&bar->flag[1], __ATOMIC_RELAXED, __HIP_MEMORY_SCOPE_AGENT) != MAGIC1)
                __builtin_amdgcn_s_sleep(8);
            (void)__hip_atomic_load(&bar->flag[0], __ATOMIC_ACQUIRE, __HIP_MEMORY_SCOPE_AGENT);
        }
        __syncthreads();
    }

    // ======================= P0: prep + mean/norm + DV=0 ====================
    {
        int gid = bid * NTHR + tid;
        if (gid < HD * CC) {              // W1T[k][c]
            int c = gid >> 6, k = gid & 63;
            W1T[(size_t)k * HD + c] = W1[gid];
        }
        if (gid < HD * HD) {              // W2T[k][c]
            int c = gid >> 7, k = gid & 127;
            W2T[(size_t)k * HD + c] = W2[gid];
        }
        if (gid < TWO_N) DV[gid] = 0;

        for (int rowt = gwave; rowt < TWO_N; rowt += NWAVES) {
            int m = rowt >> 11, n = rowt & 2047;
            const float* f = m ? f2 : f1;
            double s = 0.0;
            for (int b = 0; b < BB; ++b)
                s += (double)f[((size_t)(b * NN) + n) * CC + lane];
            double mean = s * 0.25;
            double sq = mean * mean;
            for (int d = 32; d >= 1; d >>= 1) sq += __shfl_xor(sq, d);
            double norm = sqrt(sq);
            if (norm < 1e-12) norm = 1e-12;
            double gg = mean / norm;
            g32T[((size_t)m * CC + lane) * NN + n] = (float)gg;
            gR64[((size_t)m * NN + n) * CC + lane] = gg;
        }
    }
    gbar(bar, 0);

    // ======================= P1: sims (bf16, symmetric) =====================
    {
        for (int itr = 0; itr < 2; ++itr) {
            int tile = bid * 2 + team + itr * (NBLK * 2);
            bool act = tile < 1056;
            int m = 0, bi = 0, bj = 0;
            if (act) {
                m = tile >= 528 ? 1 : 0;
                int r = tile - m * 528;
                while (r >= 32 - bi) { r -= 32 - bi; ++bi; }
                bj = bi + r;
            }
            float* As = (float*)(SMEM + (size_t)team * 32768);   // [64][64]
            float* Bs = As + 4096;                               // [64][64]
            int i0 = bi * 64, j0 = bj * 64;
            const float* g = g32T + (size_t)m * CC * NN;
            if (act) {
                #pragma unroll
                for (int q = 0; q < 16; ++q) {
                    int idx = q * 256 + tid2;
                    int k = idx >> 6, rr = idx & 63;
                    As[k * 64 + rr] = g[(size_t)k * NN + i0 + rr];
                    Bs[k * 64 + rr] = g[(size_t)k * NN + j0 + rr];
                }
            }
            __syncthreads();
            float acc[4][4] = {{0.f}};
            int tr = tid2 >> 4, tc = tid2 & 15;
            if (act) {
                #pragma unroll
                for (int k = 0; k < CC; ++k) {
                    float4 a = *((const float4*)&As[k * 64 + (tr << 2)]);
                    float4 b = *((const float4*)&Bs[k * 64 + (tc << 2)]);
                    acc[0][0] += a.x * b.x; acc[0][1] += a.x * b.y; acc[0][2] += a.x * b.z; acc[0][3] += a.x * b.w;
                    acc[1][0] += a.y * b.x; acc[1][1] += a.y * b.y; acc[1][2] += a.y * b.z; acc[1][3] += a.y * b.w;
                    acc[2][0] += a.z * b.x; acc[2][1] += a.z * b.y; acc[2][2] += a.z * b.z; acc[2][3] += a.z * b.w;
                    acc[3][0] += a.w * b.x; acc[3][1] += a.w * b.y; acc[3][2] += a.w * b.z; acc[3][3] += a.w * b.w;
                }
            }
            __syncthreads();                 // As free -> reuse as bf16 bounce
            u16* Cs = (u16*)As;              // [64][66] stride 66: conflict-free
            u16* srow = simsbf + (size_t)m * NN * NN;
            if (act) {
                #pragma unroll
                for (int x = 0; x < 4; ++x) {
                    ushort4 vd;
                    vd.x = f2bf(acc[x][0]); vd.y = f2bf(acc[x][1]);
                    vd.z = f2bf(acc[x][2]); vd.w = f2bf(acc[x][3]);
                    *((ushort4*)&srow[(size_t)(i0 + (tr << 2) + x) * NN + j0 + (tc << 2)]) = vd;
                    int cr = ((tr << 2) + x) * 66 + (tc << 2);
                    Cs[cr + 0] = vd.x; Cs[cr + 1] = vd.y;
                    Cs[cr + 2] = vd.z; Cs[cr + 3] = vd.w;
                }
            }
            __syncthreads();
            if (act) {
                #pragma unroll
                for (int q = 0; q < 4; ++q) {
                    int idx = q * 256 + tid2;
                    int cc = idx >> 4, rr4 = (idx & 15) << 2;
                    ushort4 vd;
                    vd.x = Cs[(rr4 + 0) * 66 + cc];
                    vd.y = Cs[(rr4 + 1) * 66 + cc];
                    vd.z = Cs[(rr4 + 2) * 66 + cc];
                    vd.w = Cs[(rr4 + 3) * 66 + cc];
                    *((ushort4*)&srow[(size_t)(j0 + cc) * NN + i0 + rr4]) = vd;
                }
            }
            __syncthreads();
        }
    }
    gbar(bar, 1);

    // ======================= P2: select + f64 refine ========================
    // Margin 6e-3 covers bf16 storage (<=~2e-3/side) + f32 err + bsearch window.
    {
        int* candL = (int*)(SMEM + (size_t)wid * 384);
        double* dotsL = (double*)(SMEM + (size_t)wid * 384 + 128);
        for (int row = gwave; row < TWO_N; row += NWAVES) {
            int m = row >> 11, i = row & 2047;
            int K = m ? 13 : 19;
            const u16* s = simsbf + (size_t)m * NN * NN + (size_t)i * NN;
            float sv[32];
            #pragma unroll
            for (int q = 0; q < 4; ++q) {
                uint4 w = *((const uint4*)(s + q * 512 + (lane << 3)));
                sv[q*8+0] = __uint_as_float(w.x << 16);
                sv[q*8+1] = __uint_as_float(w.x & 0xFFFF0000u);
                sv[q*8+2] = __uint_as_float(w.y << 16);
                sv[q*8+3] = __uint_as_float(w.y & 0xFFFF0000u);
                sv[q*8+4] = __uint_as_float(w.z << 16);
                sv[q*8+5] = __uint_as_float(w.z & 0xFFFF0000u);
                sv[q*8+6] = __uint_as_float(w.w << 16);
                sv[q*8+7] = __uint_as_float(w.w & 0xFFFF0000u);
            }
            float lo = -1.01f, hi = 1.01f;
            for (int it = 0; it < 12; ++it) {
                float t = 0.5f * (lo + hi);
                int c = 0;
                #pragma unroll
                for (int r = 0; r < 32; ++r)
                    c += __popcll(__ballot(sv[r] >= t));
                if (c >= K) lo = t; else hi = t;   // wave-uniform
            }
            float thr = lo - 6e-3f;
            unsigned long long ltmask = (lane == 0) ? 0ull : ((~0ull) >> (64 - lane));
            int base = 0;
            #pragma unroll
            for (int r = 0; r < 32; ++r) {
                int j = ((r >> 3) << 9) + (lane << 3) + (r & 7);
                bool p = sv[r] >= thr;
                unsigned long long mk = __ballot(p);
                int ofs = base + __popcll(mk & ltmask);
                if (p && ofs < CANDCAP) candL[ofs] = j;
                base += __popcll(mk);
            }
            int cnt = (base < CANDCAP) ? base : CANDCAP;
            __threadfence_block();
            const double* gm = gR64 + (size_t)m * NN * CC;
            double qc = gm[(size_t)i * CC + lane];
            int t4 = 0;
            for (; t4 + 3 < cnt; t4 += 4) {       // 4 independent reduce chains
                int j0c = candL[t4 + 0], j1c = candL[t4 + 1];
                int j2c = candL[t4 + 2], j3c = candL[t4 + 3];
                double p0 = qc * gm[(size_t)j0c * CC + lane];
                double p1 = qc * gm[(size_t)j1c * CC + lane];
                double p2 = qc * gm[(size_t)j2c * CC + lane];
                double p3 = qc * gm[(size_t)j3c * CC + lane];
                #pragma unroll
                for (int d = 32; d >= 1; d >>= 1) {
                    p0 += __shfl_xor(p0, d); p1 += __shfl_xor(p1, d);
                    p2 += __shfl_xor(p2, d); p3 += __shfl_xor(p3, d);
                }
                if (lane == 0) {
                    dotsL[t4 + 0] = p0; dotsL[t4 + 1] = p1;
                    dotsL[t4 + 2] = p2; dotsL[t4 + 3] = p3;
                }
            }
            for (; t4 < cnt; ++t4) {
                int j = candL[t4];
                double p = qc * gm[(size_t)j * CC + lane];
                #pragma unroll
                for (int d = 32; d >= 1; d >>= 1) p += __shfl_xor(p, d);
                if (lane == 0) dotsL[t4] = p;
            }
            __threadfence_block();
            int* knn = m ? knn2 : knn1;
            if (lane < cnt) {
                double vt = dotsL[lane]; int jt = candL[lane];
                int rank = 0;
                for (int s2 = 0; s2 < cnt; ++s2) {
                    double vs = dotsL[s2]; int js = candL[s2];
                    if (vs > vt || (vs == vt && js < jt)) ++rank;
                }
                if (rank < K) {
                    knn[(size_t)i * K + rank] = jt;
                    int w = (rank < (m ? 5 : 7)) ? 2 : 1;
                    atomicAdd(&DV[m ? NN + jt : jt], w);
                }
            }
            __threadfence_block();
        }
    }
    gbar(bar, 2);

    // ======================= P3: scan (1 wave) ==============================
    if (bid == 0 && tid < 64) {
        int ln = tid;
        int base = ln * 64;
        int s = 0;
        for (int q = 0; q < 64; ++q) s += DV[base + q];
        int x = s;
        for (int d = 1; d < 64; d <<= 1) {
            int y = __shfl_up(x, d);
            if (ln >= d) x += y;
        }
        int run = x - s;
        for (int q = 0; q < 64; ++q) {
            int v = base + q;
            offs[v] = run; cursor[v] = run;
            dvisf[v] = (float)(1.0 / sqrt((double)(DV[v] + 1)));
            run += DV[v];
        }
        if (ln == 63) offs[TWO_N] = run;
    }
    gbar(bar, 3);

    // ======================= P4: fill CSR + layer1 edge =====================
    {
        int gid = bid * NTHR + tid;
        const int M1 = NN * 19, M2 = NN * 13;
        if (gid < M1) {
            int i = gid / 19, t = gid % 19;
            int v = knn1[gid];
            int p = atomicAdd(&cursor[v], 1); entries[p] = NN + i;
            if (t < 7) { int p2 = atomicAdd(&cursor[v], 1); entries[p2] = i; }
        } else if (gid < M1 + M2) {
            int id2 = gid - M1;
            int i = id2 / 13, t = id2 % 13;
            int v = NN + knn2[id2];
            int p = atomicAdd(&cursor[v], 1); entries[p] = 3 * NN + i;
            if (t < 5) { int p2 = atomicAdd(&cursor[v], 1); entries[p2] = 2 * NN + i; }
        }

        const float4* x1 = (const float4*)f1;
        const float4* x2 = (const float4*)f2;
        float4* u4 = (float4*)ubuf;
        for (int pt = gwave; pt < TWO_N; pt += NWAVES) {
            int ff = lane & 15, b = lane >> 4;
            if (pt < NN) {
                int mv = 0; float wv = 0.f;
                if (lane < 19) { mv = knn1[(size_t)pt * 19 + lane]; wv = dvisf[mv]; }
                float ax = 0.f, ay = 0.f, az = 0.f, aw = 0.f;
                #pragma unroll
                for (int q = 0; q < 7; ++q) {
                    int mq = __shfl(mv, q); float wq = __shfl(wv, q);
                    float4 val = x1[((size_t)(b * NN) + mq) * 16 + ff];
                    ax += val.x * wq; ay += val.y * wq; az += val.z * wq; aw += val.w * wq;
                }
                u4[(size_t)pt * 64 + lane] =
                    make_float4(ax * (1.f/49.f), ay * (1.f/49.f), az * (1.f/49.f), aw * (1.f/49.f));
                #pragma unroll
                for (int q = 7; q < 19; ++q) {
                    int mq = __shfl(mv, q); float wq = __shfl(wv, q);
                    float4 val = x1[((size_t)(b * NN) + mq) * 16 + ff];
                    ax += val.x * wq; ay += val.y * wq; az += val.z * wq; aw += val.w * wq;
                }
                u4[(size_t)(NN + pt) * 64 + lane] =
                    make_float4(ax * (1.f/361.f), ay * (1.f/361.f), az * (1.f/361.f), aw * (1.f/361.f));
            } else {
                int i = pt - NN;
                int mv = 0; float wv = 0.f;
                if (lane < 13) { mv = knn2[(size_t)i * 13 + lane]; wv = dvisf[NN + mv]; }
                float ax = 0.f, ay = 0.f, az = 0.f, aw = 0.f;
                #pragma unroll
                for (int q = 0; q < 5; ++q) {
                    int mq = __shfl(mv, q); float wq = __shfl(wv, q);
                    float4 val = x2[((size_t)(b * NN) + mq) * 16 + ff];
                    ax += val.x * wq; ay += val.y * wq; az += val.z * wq; aw += val.w * wq;
                }
                u4[(size_t)(2 * NN + i) * 64 + lane] =
                    make_float4(ax * (1.f/25.f), ay * (1.f/25.f), az * (1.f/25.f), aw * (1.f/25.f));
                #pragma unroll
                for (int q = 5; q < 13; ++q) {
                    int mq = __shfl(mv, q); float wq = __shfl(wv, q);
                    float4 val = x2[((size_t)(b * NN) + mq) * 16 + ff];
                    ax += val.x * wq; ay += val.y * wq; az += val.z * wq; aw += val.w * wq;
                }
                u4[(size_t)(3 * NN + i) * 64 + lane] =
                    make_float4(ax * (1.f/169.f), ay * (1.f/169.f), az * (1.f/169.f), aw * (1.f/169.f));
            }
        }
    }
    gbar(bar, 4);

    // ============ P5: node1 -> LDS xT -> gemm1 -> zbuf -> gemm2 -> ybuf =====
    // Team gteam owns nodes 8g..8g+7 == r'-rows 32g..32g+31; z rows are
    // team-local so gemm1->gemm2 needs only block-level sync.
    {
        float* wT = (float*)SMEM;                              // [64][132]
        float* xT = ((float*)(SMEM + 33792)) + team * 2112;    // [64][33] per team
        #pragma unroll
        for (int p = 0; p < 16; ++p) {                         // stage W1T
            int idx = p * NTHR + tid;
            wT[(idx >> 7) * 132 + (idx & 127)] = W1T[idx];
        }
        int gteam = bid * 2 + team;
        bool act = gteam < 512;
        int v0 = gteam * 8;
        int g0 = gteam * 32;
        if (act) {
            const float4* u4 = (const float4*)ubuf;
            const float4* x1 = (const float4*)f1;
            const float4* x2 = (const float4*)f2;
            #pragma unroll
            for (int itp = 0; itp < 2; ++itp) {
                int item = itp * 256 + tid2;
                int vl = item >> 6, l6 = item & 63;
                int ff = l6 & 15, b = l6 >> 4;
                int v = v0 + vl;
                int s = offs[v], e_end = offs[v + 1];
                float a0x=0,a0y=0,a0z=0,a0w=0, a1x=0,a1y=0,a1z=0,a1w=0;
                float a2x=0,a2y=0,a2z=0,a2w=0, a3x=0,a3y=0,a3z=0,a3w=0;
                int p = s;
                for (; p + 3 < e_end; p += 4) {
                    int e0 = entries[p], e1 = entries[p+1], e2 = entries[p+2], e3 = entries[p+3];
                    float4 v0v = u4[(size_t)e0 * 64 + l6];
                    float4 v1v = u4[(size_t)e1 * 64 + l6];
                    float4 v2v = u4[(size_t)e2 * 64 + l6];
                    float4 v3v = u4[(size_t)e3 * 64 + l6];
                    a0x+=v0v.x;a0y+=v0v.y;a0z+=v0v.z;a0w+=v0v.w;
                    a1x+=v1v.x;a1y+=v1v.y;a1z+=v1v.z;a1w+=v1v.w;
                    a2x+=v2v.x;a2y+=v2v.y;a2z+=v2v.z;a2w+=v2v.w;
                    a3x+=v3v.x;a3y+=v3v.y;a3z+=v3v.z;a3w+=v3v.w;
                }
                for (; p < e_end; ++p) {
                    float4 vv = u4[(size_t)entries[p] * 64 + l6];
                    a0x+=vv.x;a0y+=vv.y;a0z+=vv.z;a0w+=vv.w;
                }
                float ax = (a0x+a1x)+(a2x+a3x);
                float ay = (a0y+a1y)+(a2y+a3y);
                float az = (a0z+a1z)+(a2z+a3z);
                float aw = (a0w+a1w)+(a2w+a3w);
                int partner = (v < NN) ? v + NN : v - NN;
                float w0 = dvisf[v], w1 = dvisf[partner];
                float4 xv = (v < NN) ? x1[((size_t)(b*NN) + v) * 16 + ff]
                                     : x2[((size_t)(b*NN) + (v - NN)) * 16 + ff];
                float4 xp = (partner < NN) ? x1[((size_t)(b*NN) + partner) * 16 + ff]
                                           : x2[((size_t)(b*NN) + (partner - NN)) * 16 + ff];
                ax += 0.25f * (xv.x * w0 + xp.x * w1);
                ay += 0.25f * (xv.y * w0 + xp.y * w1);
                az += 0.25f * (xv.z * w0 + xp.z * w1);
                aw += 0.25f * (xv.w * w0 + xp.w * w1);
                ax *= w0; ay *= w0; az *= w0; aw *= w0;
                int rloc = vl * 4 + b;
                int kb = ff * 4;
                xT[(kb + 0) * 33 + rloc] = ax;
                xT[(kb + 1) * 33 + rloc] = ay;
                xT[(kb + 2) * 33 + rloc] = az;
                xT[(kb + 3) * 33 + rloc] = aw;
            }
        }
        __syncthreads();
        int tr = tid2 >> 5, tc = tid2 & 31;
        int r0 = tr * 4, c0 = tc * 4;
        if (act) {                                              // gemm1 + relu
            float acc[4][4] = {{0.f}};
            #pragma unroll
            for (int k = 0; k < CC; ++k) {
                float xr0 = xT[k*33 + r0+0], xr1 = xT[k*33 + r0+1];
                float xr2 = xT[k*33 + r0+2], xr3 = xT[k*33 + r0+3];
                float4 w = *((const float4*)&wT[k * 132 + c0]);
                acc[0][0]+=xr0*w.x; acc[0][1]+=xr0*w.y; acc[0][2]+=xr0*w.z; acc[0][3]+=xr0*w.w;
                acc[1][0]+=xr1*w.x; acc[1][1]+=xr1*w.y; acc[1][2]+=xr1*w.z; acc[1][3]+=xr1*w.w;
                acc[2][0]+=xr2*w.x; acc[2][1]+=xr2*w.y; acc[2][2]+=xr2*w.z; acc[2][3]+=xr2*w.w;
                acc[3][0]+=xr3*w.x; acc[3][1]+=xr3*w.y; acc[3][2]+=xr3*w.z; acc[3][3]+=xr3*w.w;
            }
            #pragma unroll
            for (int i = 0; i < 4; ++i) {
                float4 v = make_float4(fmaxf(acc[i][0],0.f), fmaxf(acc[i][1],0.f),
                                       fmaxf(acc[i][2],0.f), fmaxf(acc[i][3],0.f));
                *((float4*)&zbuf[(size_t)(g0 + r0 + i) * HD + c0]) = v;
            }
        }
        // gemm2 (z rows are team-local; block-level sync only)
        float* zT = xT;                                         // reuse [64][33]
        float acc2[4][4] = {{0.f}};
        for (int kc = 0; kc < 2; ++kc) {
            __syncthreads();                                    // wT/zT reuse safe
            #pragma unroll
            for (int p = 0; p < 16; ++p) {                      // stage W2T chunk
                int idx = p * NTHR + tid;
                int k = idx >> 7, c = idx & 127;
                wT[k * 132 + c] = W2T[(size_t)(kc * 64 + k) * HD + c];
            }
            if (act) {
                #pragma unroll
                for (int q = 0; q < 8; ++q) {
                    int idx = q * 256 + tid2;
                    int row = idx >> 6, k = idx & 63;
                    zT[k * 33 + row] = zbuf[(size_t)(g0 + row) * HD + kc * 64 + k];
                }
            }
            __syncthreads();
            if (act) {
                #pragma unroll
                for (int k = 0; k < 64; ++k) {
                    float zr0 = zT[k*33 + r0+0], zr1 = zT[k*33 + r0+1];
                    float zr2 = zT[k*33 + r0+2], zr3 = zT[k*33 + r0+3];
                    float4 w = *((const float4*)&wT[k * 132 + c0]);
                    acc2[0][0]+=zr0*w.x; acc2[0][1]+=zr0*w.y; acc2[0][2]+=zr0*w.z; acc2[0][3]+=zr0*w.w;
                    acc2[1][0]+=zr1*w.x; acc2[1][1]+=zr1*w.y; acc2[1][2]+=zr1*w.z; acc2[1][3]+=zr1*w.w;
                    acc2[2][0]+=zr2*w.x; acc2[2][1]+=zr2*w.y; acc2[2][2]+=zr2*w.z; acc2[2][3]+=zr2*w.w;
                    acc2[3][0]+=zr3*w.x; acc2[3][1]+=zr3*w.y; acc2[3][2]+=zr3*w.z; acc2[3][3]+=zr3*w.w;
                }
            }
        }
        if (act) {
            #pragma unroll
            for (int i = 0; i < 4; ++i) {
                float4 v = make_float4(acc2[i][0], acc2[i][1], acc2[i][2], acc2[i][3]);
                *((float4*)&ybuf[(size_t)(g0 + r0 + i) * HD + c0]) = v;
            }
        }
    }
    gbar(bar, 5);

    // ======================= P6: layer2 edge (on y) =========================
    {
        const float4* y4 = (const float4*)ybuf;
        float4* u4 = (float4*)ubuf;
        int wteam = wid >> 1, wsub = wid & 1;
        int gt2 = bid * 4 + wteam;                 // 2-wave teams
        for (int pt = gt2; pt < TWO_N; pt += NBLK * 4) {
            int ff = lane & 31;
            int b = wsub * 2 + (lane >> 5);
            int bo = b * 32 + ff;
            if (pt < NN) {
                int mv = 0; float wv = 0.f;
                if (lane < 19) { mv = knn1[(size_t)pt * 19 + lane]; wv = dvisf[mv]; }
                float ax=0,ay=0,az=0,aw=0;
                #pragma unroll
                for (int q = 0; q < 7; ++q) {
                    int mq = __shfl(mv, q); float wq = __shfl(wv, q);
                    float4 val = y4[(size_t)mq * 128 + bo];
                    ax += val.x*wq; ay += val.y*wq; az += val.z*wq; aw += val.w*wq;
                }
                u4[(size_t)pt * 128 + bo] =
                    make_float4(ax*(1.f/49.f), ay*(1.f/49.f), az*(1.f/49.f), aw*(1.f/49.f));
                #pragma unroll
                for (int q = 7; q < 19; ++q) {
                    int mq = __shfl(mv, q); float wq = __shfl(wv, q);
                    float4 val = y4[(size_t)mq * 128 + bo];
                    ax += val.x*wq; ay += val.y*wq; az += val.z*wq; aw += val.w*wq;
                }
                u4[(size_t)(NN + pt) * 128 + bo] =
                    make_float4(ax*(1.f/361.f), ay*(1.f/361.f), az*(1.f/361.f), aw*(1.f/361.f));
            } else {
                int i = pt - NN;
                int mv = 0; float wv = 0.f;
                if (lane < 13) { mv = NN + knn2[(size_t)i * 13 + lane]; wv = dvisf[mv]; }
                float ax=0,ay=0,az=0,aw=0;
                #pragma unroll
                for (int q = 0; q < 5; ++q) {
                    int mq = __shfl(mv, q); float wq = __shfl(wv, q);
                    float4 val = y4[(size_t)mq * 128 + bo];
                    ax += val.x*wq; ay += val.y*wq; az += val.z*wq; aw += val.w*wq;
                }
                u4[(size_t)(2 * NN + i) * 128 + bo] =
                    make_float4(ax*(1.f/25.f), ay*(1.f/25.f), az*(1.f/25.f), aw*(1.f/25.f));
                #pragma unroll
                for (int q = 5; q < 13; ++q) {
                    int mq = __shfl(mv, q); float wq = __shfl(wv, q);
                    float4 val = y4[(size_t)mq * 128 + bo];
                    ax += val.x*wq; ay += val.y*wq; az += val.z*wq; aw += val.w*wq;
                }
                u4[(size_t)(3 * NN + i) * 128 + bo] =
                    make_float4(ax*(1.f/169.f), ay*(1.f/169.f), az*(1.f/169.f), aw*(1.f/169.f));
            }
        }
    }
    gbar(bar, 6);

    // ======================= P7: layer2 node -> out =========================
    {
        const float4* u4 = (const float4*)ubuf;
        const float4* y4 = (const float4*)ybuf;
        float4* outp4 = (float4*)out;
        int wteam = wid >> 1, wsub = wid & 1;
        int gt2 = bid * 4 + wteam;
        for (int v = gt2; v < TWO_N; v += NBLK * 4) {
            int ff = lane & 31;
            int b = wsub * 2 + (lane >> 5);
            int bo = b * 32 + ff;
            int s = offs[v], e_end = offs[v + 1];
            float a0x=0,a0y=0,a0z=0,a0w=0, a1x=0,a1y=0,a1z=0,a1w=0;
            float a2x=0,a2y=0,a2z=0,a2w=0, a3x=0,a3y=0,a3z=0,a3w=0;
            int p = s;
            for (; p + 3 < e_end; p += 4) {
                int e0 = entries[p], e1 = entries[p+1], e2 = entries[p+2], e3 = entries[p+3];
                float4 v0 = u4[(size_t)e0 * 128 + bo];
                float4 v1 = u4[(size_t)e1 * 128 + bo];
                float4 v2 = u4[(size_t)e2 * 128 + bo];
                float4 v3 = u4[(size_t)e3 * 128 + bo];
                a0x+=v0.x;a0y+=v0.y;a0z+=v0.z;a0w+=v0.w;
                a1x+=v1.x;a1y+=v1.y;a1z+=v1.z;a1w+=v1.w;
                a2x+=v2.x;a2y+=v2.y;a2z+=v2.z;a2w+=v2.w;
                a3x+=v3.x;a3y+=v3.y;a3z+=v3.z;a3w+=v3.w;
            }
            for (; p < e_end; ++p) {
                float4 v0 = u4[(size_t)entries[p] * 128 + bo];
                a0x+=v0.x;a0y+=v0.y;a0z+=v0.z;a0w+=v0.w;
            }
            float ax = (a0x+a1x)+(a2x+a3x);
            float ay = (a0y+a1y)+(a2y+a3y);
            float az = (a0z+a1z)+(a2z+a3z);
            float aw = (a0w+a1w)+(a2w+a3w);
            int partner = (v < NN) ? v + NN : v - NN;
            float w0 = dvisf[v], w1 = dvisf[partner];
            float4 yv = y4[(size_t)v * 128 + bo];
            float4 yp = y4[(size_t)partner * 128 + bo];
            ax += 0.25f * (yv.x * w0 + yp.x * w1);
            ay += 0.25f * (yv.y * w0 + yp.y * w1);
            az += 0.25f * (yv.z * w0 + yp.z * w1);
            aw += 0.25f * (yv.w * w0 + yp.w * w1);
            ax *= w0; ay *= w0; az *= w0; aw *= w0;
            float4 res = make_float4(fmaxf(ax,0.f), fmaxf(ay,0.f),
                                     fmaxf(az,0.f), fmaxf(aw,0.f));
            size_t o;
            if (v < NN) o = ((size_t)(b * NN + v)) * 32 + ff;
            else        o = (size_t)BB * NN * 32 + ((size_t)(b * NN + (v - NN))) * 32 + ff;
            outp4[o] = res;
        }
    }

    // close the handshake so a replay without re-poisoning can't see stale magic
    if (bid == 0 && tid == 0) {
        __hip_atomic_store(&bar->flag[0], 0, __ATOMIC_RELEASE, __HIP_MEMORY_SCOPE_AGENT);
        __hip_atomic_store(&bar->flag[1], 0, __ATOMIC_RELEASE, __HIP_MEMORY_SCOPE_AGENT);
    }
}

// ---------------------------------------------------------------------------
extern "C" void kernel_launch(void* const* d_in, const int* in_sizes, int n_in,
                              void* d_out, int out_size, void* d_ws, size_t ws_size,
                              hipStream_t stream) {
    const float* f1 = (const float*)d_in[0];
    const float* f2 = (const float*)d_in[1];
    const float* W1 = (const float*)d_in[2];
    const float* W2 = (const float*)d_in[3];
    float* out = (float*)d_out;

    char* ws = (char*)d_ws;
    size_t off = 0;
    auto alloc = [&](size_t bytes) -> void* {
        void* p = ws + off;
        off = (off + bytes + 255) & ~(size_t)255;
        return p;
    };
    BarMem* bar    = (BarMem*)alloc(sizeof(BarMem));
    float*  g32T   = (float*)alloc((size_t)2 * CC * NN * 4);          // 1 MB
    double* gR64   = (double*)alloc((size_t)2 * NN * CC * 8);         // 2 MB
    u16*    simsbf = (u16*)alloc((size_t)2 * NN * NN * 2);            // 16 MB
    float*  ybuf   = (float*)alloc((size_t)BB * TWO_N * HD * 4);      // 8 MB
    float*  zbuf   = (float*)alloc((size_t)BB * TWO_N * HD * 4);      // 8 MB
    float*  ubuf   = (float*)alloc((size_t)BB * 4 * NN * HD * 4);     // 16 MB
    float*  W1T    = (float*)alloc((size_t)CC * HD * 4);
    float*  W2T    = (float*)alloc((size_t)HD * HD * 4);
    float*  dvisf  = (float*)alloc((size_t)TWO_N * 4);
    int*    knn1   = (int*)alloc((size_t)NN * 19 * 4);
    int*    knn2   = (int*)alloc((size_t)NN * 13 * 4);
    int*    DV     = (int*)alloc((size_t)TWO_N * 4);
    int*    offs   = (int*)alloc((size_t)(TWO_N + 1) * 4);
    int*    cursor = (int*)alloc((size_t)TWO_N * 4);
    int*    entries= (int*)alloc((size_t)(NN * 26 + NN * 18) * 4);

    k_uber<<<dim3(NBLK), dim3(NTHR), 0, stream>>>(
        f1, f2, W1, W2, bar, g32T, gR64, simsbf, ybuf, zbuf, ubuf,
        W1T, W2T, dvisf, knn1, knn2, DV, offs, cursor, entries, out);
}

// Round 4
// 200.074 us; speedup vs baseline: 3.8812x; 1.7217x over previous
//
#include <hip/hip_runtime.h>
#include <math.h>

// Problem constants
#define NN 2048      // nodes per modality
#define TWO_N 4096   // total nodes
#define BB 4         // batch
#define CC 64        // input feature dim
#define HD 128       // hidden dim
#define CANDCAP 32   // max candidates per row after margin filter

typedef unsigned short u16;
typedef _Float16 h16;
union H4 { ushort4 u; h16 h[4]; };

__device__ __forceinline__ u16 f2bf(float x) {   // RN-even f32 -> bf16
    unsigned u = __float_as_uint(x);
    u += 0x7FFFu + ((u >> 16) & 1u);
    return (u16)(u >> 16);
}

// ---------------------------------------------------------------------------
// 1) batch-mean + L2-normalize; also: DV zero, W1/W2 transpose, x -> fp16.
//    grid (NN, 2) x 64 threads.
// ---------------------------------------------------------------------------
__global__ void k_mean_norm(const float* __restrict__ f1, const float* __restrict__ f2,
                            const float* __restrict__ W1, const float* __restrict__ W2,
                            float* __restrict__ g32T, double* __restrict__ gR64,
                            u16* __restrict__ xh,
                            float* __restrict__ W1T, float* __restrict__ W2T,
                            int* __restrict__ DV) {
    int n = blockIdx.x;           // node
    int m = blockIdx.y;           // modality
    int c = threadIdx.x;          // 64 threads = 1 wave
    if (m == 0 && n < 64) DV[n * 64 + c] = 0;   // covers 0..4095
    if (m == 1) {
        if (n < 128) {            // W1T[k][o] from W1[o][k], 8192 elems
            int idx = n * 64 + c;
            W1T[(size_t)(idx & 63) * HD + (idx >> 6)] = W1[idx];
        } else if (n < 384) {     // W2T[k][o] from W2[o][k], 16384 elems
            int idx = (n - 128) * 64 + c;
            W2T[(size_t)(idx & 127) * HD + (idx >> 7)] = W2[idx];
        }
    }
    const float* f = m ? f2 : f1;
    float xv[BB];
    double s = 0.0;
    for (int b = 0; b < BB; ++b) {
        float v = f[((size_t)(b * NN) + n) * CC + c];
        xv[b] = v; s += (double)v;
    }
    h16* xrow = (h16*)(xh + ((size_t)(m * NN + n)) * (BB * CC));
    for (int b = 0; b < BB; ++b) xrow[b * CC + c] = (h16)xv[b];
    double mean = s * 0.25;
    double sq = mean * mean;
    for (int d = 32; d >= 1; d >>= 1) sq += __shfl_xor(sq, d);
    double norm = sqrt(sq);
    if (norm < 1e-12) norm = 1e-12;
    double g = mean / norm;
    g32T[((size_t)m * CC + c) * NN + n] = (float)g;
    gR64[((size_t)m * NN + n) * CC + c] = g;
}

// ---------------------------------------------------------------------------
// 2) f32 sims GEMM, symmetric (upper-tri tiles), bf16 store + mirror via LDS.
// ---------------------------------------------------------------------------
__global__ void __launch_bounds__(256)
k_sims(const float* __restrict__ g32T, u16* __restrict__ simsbf) {
    __shared__ float As[64 * 64];   // 16 KB
    __shared__ float Bs[64 * 64];   // 16 KB
    int m  = blockIdx.y;
    int bi = blockIdx.x >> 5, bj = blockIdx.x & 31;
    if (bi > bj) return;            // uniform exit before barriers
    int i0 = bi * 64, j0 = bj * 64;
    const float* g = g32T + (size_t)m * CC * NN;
    int tid = threadIdx.x;
    #pragma unroll
    for (int q = 0; q < 16; ++q) {
        int idx = q * 256 + tid;
        int k = idx >> 6, r = idx & 63;
        As[k * 64 + r] = g[(size_t)k * NN + i0 + r];
        Bs[k * 64 + r] = g[(size_t)k * NN + j0 + r];
    }
    __syncthreads();
    int tr = tid >> 4, tc = tid & 15;
    float acc[4][4] = {{0.f}};
    #pragma unroll
    for (int k = 0; k < CC; ++k) {
        float4 a = *((const float4*)&As[k * 64 + (tr << 2)]);
        float4 b = *((const float4*)&Bs[k * 64 + (tc << 2)]);
        acc[0][0] += a.x * b.x; acc[0][1] += a.x * b.y; acc[0][2] += a.x * b.z; acc[0][3] += a.x * b.w;
        acc[1][0] += a.y * b.x; acc[1][1] += a.y * b.y; acc[1][2] += a.y * b.z; acc[1][3] += a.y * b.w;
        acc[2][0] += a.z * b.x; acc[2][1] += a.z * b.y; acc[2][2] += a.z * b.z; acc[2][3] += a.z * b.w;
        acc[3][0] += a.w * b.x; acc[3][1] += a.w * b.y; acc[3][2] += a.w * b.z; acc[3][3] += a.w * b.w;
    }
    __syncthreads();                // As free -> reuse as bf16 bounce [64][66]
    u16* Cs = (u16*)As;
    u16* srow = simsbf + (size_t)m * NN * NN;
    #pragma unroll
    for (int x = 0; x < 4; ++x) {
        ushort4 vd;
        vd.x = f2bf(acc[x][0]); vd.y = f2bf(acc[x][1]);
        vd.z = f2bf(acc[x][2]); vd.w = f2bf(acc[x][3]);
        *((ushort4*)&srow[(size_t)(i0 + (tr << 2) + x) * NN + j0 + (tc << 2)]) = vd;
        int cr = ((tr << 2) + x) * 66 + (tc << 2);
        Cs[cr + 0] = vd.x; Cs[cr + 1] = vd.y; Cs[cr + 2] = vd.z; Cs[cr + 3] = vd.w;
    }
    __syncthreads();
    #pragma unroll
    for (int q = 0; q < 4; ++q) {
        int idx = q * 256 + tid;
        int cc = idx >> 4, rr4 = (idx & 15) << 2;
        ushort4 vd;
        vd.x = Cs[(rr4 + 0) * 66 + cc];
        vd.y = Cs[(rr4 + 1) * 66 + cc];
        vd.z = Cs[(rr4 + 2) * 66 + cc];
        vd.w = Cs[(rr4 + 3) * 66 + cc];
        *((ushort4*)&srow[(size_t)(j0 + cc) * NN + i0 + rr4]) = vd;
    }
}

// ---------------------------------------------------------------------------
// 3) select (bf16, margin 6e-3: covers bf16 round 2e-3/side + window) +
//    f64-exact refine. Superset argument as R2/R3 (passed, absmax unchanged).
// ---------------------------------------------------------------------------
__global__ void __launch_bounds__(512)
k_selref(const u16* __restrict__ simsbf, const double* __restrict__ gR64,
         int* __restrict__ knn1, int* __restrict__ knn2, int* __restrict__ DV) {
    __shared__ int    candL[8][CANDCAP];
    __shared__ double dotsL[8][CANDCAP];
    int wave = threadIdx.x >> 6, lane = threadIdx.x & 63;
    int row = blockIdx.x * 8 + wave;    // 0..4095
    int m = row >> 11, i = row & 2047;
    int K = m ? 13 : 19;
    const u16* s = simsbf + (size_t)m * NN * NN + (size_t)i * NN;
    float sv[32];
    #pragma unroll
    for (int q = 0; q < 4; ++q) {
        uint4 w = *((const uint4*)(s + q * 512 + (lane << 3)));
        sv[q*8+0] = __uint_as_float(w.x << 16);
        sv[q*8+1] = __uint_as_float(w.x & 0xFFFF0000u);
        sv[q*8+2] = __uint_as_float(w.y << 16);
        sv[q*8+3] = __uint_as_float(w.y & 0xFFFF0000u);
        sv[q*8+4] = __uint_as_float(w.z << 16);
        sv[q*8+5] = __uint_as_float(w.z & 0xFFFF0000u);
        sv[q*8+6] = __uint_as_float(w.w << 16);
        sv[q*8+7] = __uint_as_float(w.w & 0xFFFF0000u);
    }
    float lo = -1.01f, hi = 1.01f;
    for (int it = 0; it < 12; ++it) {
        float t = 0.5f * (lo + hi);
        int c = 0;
        #pragma unroll
        for (int r = 0; r < 32; ++r)
            c += __popcll(__ballot(sv[r] >= t));
        if (c >= K) lo = t; else hi = t;   // wave-uniform
    }
    float thr = lo - 6e-3f;
    unsigned long long ltmask = (lane == 0) ? 0ull : ((~0ull) >> (64 - lane));
    int base = 0;
    #pragma unroll
    for (int r = 0; r < 32; ++r) {
        int j = ((r >> 3) << 9) + (lane << 3) + (r & 7);
        bool p = sv[r] >= thr;
        unsigned long long mk = __ballot(p);
        int ofs = base + __popcll(mk & ltmask);
        if (p && ofs < CANDCAP) candL[wave][ofs] = j;
        base += __popcll(mk);
    }
    int cnt = (base < CANDCAP) ? base : CANDCAP;
    __syncthreads();
    const double* gm = gR64 + (size_t)m * NN * CC;
    double qc = gm[(size_t)i * CC + lane];
    int t4 = 0;
    for (; t4 + 3 < cnt; t4 += 4) {       // 4 independent reduce chains
        int j0c = candL[wave][t4 + 0], j1c = candL[wave][t4 + 1];
        int j2c = candL[wave][t4 + 2], j3c = candL[wave][t4 + 3];
        double p0 = qc * gm[(size_t)j0c * CC + lane];
        double p1 = qc * gm[(size_t)j1c * CC + lane];
        double p2 = qc * gm[(size_t)j2c * CC + lane];
        double p3 = qc * gm[(size_t)j3c * CC + lane];
        #pragma unroll
        for (int d = 32; d >= 1; d >>= 1) {
            p0 += __shfl_xor(p0, d); p1 += __shfl_xor(p1, d);
            p2 += __shfl_xor(p2, d); p3 += __shfl_xor(p3, d);
        }
        if (lane == 0) {
            dotsL[wave][t4 + 0] = p0; dotsL[wave][t4 + 1] = p1;
            dotsL[wave][t4 + 2] = p2; dotsL[wave][t4 + 3] = p3;
        }
    }
    for (; t4 < cnt; ++t4) {
        int j = candL[wave][t4];
        double p = qc * gm[(size_t)j * CC + lane];
        #pragma unroll
        for (int d = 32; d >= 1; d >>= 1) p += __shfl_xor(p, d);
        if (lane == 0) dotsL[wave][t4] = p;
    }
    __syncthreads();
    int* knn = m ? knn2 : knn1;
    if (lane < cnt) {
        double vt = dotsL[wave][lane]; int jt = candL[wave][lane];
        int rank = 0;
        for (int s2 = 0; s2 < cnt; ++s2) {
            double vs = dotsL[wave][s2]; int js = candL[wave][s2];
            if (vs > vt || (vs == vt && js < jt)) ++rank;
        }
        if (rank < K) {
            knn[(size_t)i * K + rank] = jt;
            int w = (rank < (m ? 5 : 7)) ? 2 : 1;
            atomicAdd(&DV[m ? NN + jt : jt], w);
        }
    }
}

// ---------------------------------------------------------------------------
// 4) exclusive scan -> CSR offsets; dvisf = 1/sqrt(DV+1).
// ---------------------------------------------------------------------------
__global__ void k_scan(const int* __restrict__ DV, int* __restrict__ offs,
                       int* __restrict__ cursor, float* __restrict__ dvisf) {
    int lane = threadIdx.x;      // 64
    int base = lane * 64;
    int s = 0;
    for (int q = 0; q < 64; ++q) s += DV[base + q];
    int x = s;
    for (int d = 1; d < 64; d <<= 1) {
        int y = __shfl_up(x, d);
        if (lane >= d) x += y;
    }
    int run = x - s;
    for (int q = 0; q < 64; ++q) {
        int v = base + q;
        offs[v] = run; cursor[v] = run;
        dvisf[v] = (float)(1.0 / sqrt((double)(DV[v] + 1)));
        run += DV[v];
    }
    if (lane == 63) offs[TWO_N] = run;
}

// ---------------------------------------------------------------------------
// 5) fill CSR transpose.
// ---------------------------------------------------------------------------
__global__ void k_fill(const int* __restrict__ knn1, const int* __restrict__ knn2,
                       int* __restrict__ cursor, int* __restrict__ entries) {
    int id = blockIdx.x * blockDim.x + threadIdx.x;
    const int M1 = NN * 19, M2 = NN * 13;
    if (id < M1) {
        int i = id / 19, t = id % 19;
        int v = knn1[id];
        int p = atomicAdd(&cursor[v], 1); entries[p] = NN + i;
        if (t < 7) { int p2 = atomicAdd(&cursor[v], 1); entries[p2] = i; }
    } else if (id < M1 + M2) {
        int id2 = id - M1;
        int i = id2 / 13, t = id2 % 13;
        int v = NN + knn2[id2];
        int p = atomicAdd(&cursor[v], 1); entries[p] = 3 * NN + i;
        if (t < 5) { int p2 = atomicAdd(&cursor[v], 1); entries[p2] = 2 * NN + i; }
    }
}

// ---------------------------------------------------------------------------
// 6) layer1 edge on fp16 x-hat rows (512 B). Grid 2NN x 64; shfl members.
// ---------------------------------------------------------------------------
__global__ void k_edgeX(const u16* __restrict__ xh, const float* __restrict__ dvisf,
                        const int* __restrict__ knn1, const int* __restrict__ knn2,
                        u16* __restrict__ uh1) {
    int blk = blockIdx.x;
    int t = threadIdx.x;            // 64; owns 4 halves of the 256-half row
    int off = t * 4;
    if (blk < NN) {                 // m1 pair: k6 (7) + k18 (19)
        int mv = 0; float wv = 0.f;
        if (t < 19) { mv = knn1[(size_t)blk * 19 + t]; wv = dvisf[mv]; }
        float a0=0,a1=0,a2=0,a3=0;
        #pragma unroll
        for (int q = 0; q < 7; ++q) {
            int mq = __shfl(mv, q); float wq = __shfl(wv, q);
            H4 hv; hv.u = *((const ushort4*)(xh + (size_t)mq * 256 + off));
            a0 += (float)hv.h[0]*wq; a1 += (float)hv.h[1]*wq;
            a2 += (float)hv.h[2]*wq; a3 += (float)hv.h[3]*wq;
        }
        { H4 ho; ho.h[0]=(h16)(a0*(1.f/49.f)); ho.h[1]=(h16)(a1*(1.f/49.f));
          ho.h[2]=(h16)(a2*(1.f/49.f)); ho.h[3]=(h16)(a3*(1.f/49.f));
          *((ushort4*)(uh1 + (size_t)blk * 256 + off)) = ho.u; }
        #pragma unroll
        for (int q = 7; q < 19; ++q) {
            int mq = __shfl(mv, q); float wq = __shfl(wv, q);
            H4 hv; hv.u = *((const ushort4*)(xh + (size_t)mq * 256 + off));
            a0 += (float)hv.h[0]*wq; a1 += (float)hv.h[1]*wq;
            a2 += (float)hv.h[2]*wq; a3 += (float)hv.h[3]*wq;
        }
        { H4 ho; ho.h[0]=(h16)(a0*(1.f/361.f)); ho.h[1]=(h16)(a1*(1.f/361.f));
          ho.h[2]=(h16)(a2*(1.f/361.f)); ho.h[3]=(h16)(a3*(1.f/361.f));
          *((ushort4*)(uh1 + (size_t)(NN + blk) * 256 + off)) = ho.u; }
    } else {                        // m2 pair: k4 (5) + k12 (13)
        int i = blk - NN;
        int mv = 0; float wv = 0.f;
        if (t < 13) { mv = knn2[(size_t)i * 13 + t]; wv = dvisf[NN + mv]; }
        float a0=0,a1=0,a2=0,a3=0;
        #pragma unroll
        for (int q = 0; q < 5; ++q) {
            int mq = __shfl(mv, q); float wq = __shfl(wv, q);
            H4 hv; hv.u = *((const ushort4*)(xh + (size_t)(NN + mq) * 256 + off));
            a0 += (float)hv.h[0]*wq; a1 += (float)hv.h[1]*wq;
            a2 += (float)hv.h[2]*wq; a3 += (float)hv.h[3]*wq;
        }
        { H4 ho; ho.h[0]=(h16)(a0*(1.f/25.f)); ho.h[1]=(h16)(a1*(1.f/25.f));
          ho.h[2]=(h16)(a2*(1.f/25.f)); ho.h[3]=(h16)(a3*(1.f/25.f));
          *((ushort4*)(uh1 + (size_t)(2 * NN + i) * 256 + off)) = ho.u; }
        #pragma unroll
        for (int q = 5; q < 13; ++q) {
            int mq = __shfl(mv, q); float wq = __shfl(wv, q);
            H4 hv; hv.u = *((const ushort4*)(xh + (size_t)(NN + mq) * 256 + off));
            a0 += (float)hv.h[0]*wq; a1 += (float)hv.h[1]*wq;
            a2 += (float)hv.h[2]*wq; a3 += (float)hv.h[3]*wq;
        }
        { H4 ho; ho.h[0]=(h16)(a0*(1.f/169.f)); ho.h[1]=(h16)(a1*(1.f/169.f));
          ho.h[2]=(h16)(a2*(1.f/169.f)); ho.h[3]=(h16)(a3*(1.f/169.f));
          *((ushort4*)(uh1 + (size_t)(3 * NN + i) * 256 + off)) = ho.u; }
    }
}

// ---------------------------------------------------------------------------
// 7) FUSED node1 -> gemm1(relu) -> gemm2 -> yh (fp16). 512 blocks x 256 thr.
//    Block owns 8 nodes = 32 r'-rows; z lives in LDS (no zbuf/aggx).
// ---------------------------------------------------------------------------
__global__ void __launch_bounds__(256)
k_nodeGemm(const u16* __restrict__ uh1,
           const float* __restrict__ f1, const float* __restrict__ f2,
           const float* __restrict__ dvisf,
           const int* __restrict__ offs, const int* __restrict__ entries,
           const float* __restrict__ W1T, const float* __restrict__ W2T,
           u16* __restrict__ yh) {
    __shared__ float wT[64 * 132];   // 33.8 KB
    __shared__ float xT[64 * 33];    //  8.4 KB
    __shared__ float zT[128 * 33];   // 16.9 KB
    int tid = threadIdx.x;
    int bid = blockIdx.x;            // 0..511
    int v0 = bid * 8, g0 = bid * 32;
    #pragma unroll
    for (int p = 0; p < 32; ++p) {   // stage W1T
        int idx = p * 256 + tid;
        wT[(idx >> 7) * 132 + (idx & 127)] = W1T[idx];
    }
    const float4* x1 = (const float4*)f1;
    const float4* x2 = (const float4*)f2;
    #pragma unroll
    for (int it = 0; it < 2; ++it) { // 512 items = 8 nodes x 64 lanes
        int item = it * 256 + tid;
        int vl = item >> 6, l6 = item & 63;
        int b = l6 >> 4, f4i = l6 & 15;
        int c4 = f4i << 2;
        int v = v0 + vl;
        int s = offs[v], e_end = offs[v + 1];
        float A0[4] = {0,0,0,0}, A1[4] = {0,0,0,0};
        float A2[4] = {0,0,0,0}, A3[4] = {0,0,0,0};
        int p = s;
        for (; p + 3 < e_end; p += 4) {
            H4 h0, h1, h2, h3;
            h0.u = *((const ushort4*)(uh1 + (size_t)entries[p+0] * 256 + l6 * 4));
            h1.u = *((const ushort4*)(uh1 + (size_t)entries[p+1] * 256 + l6 * 4));
            h2.u = *((const ushort4*)(uh1 + (size_t)entries[p+2] * 256 + l6 * 4));
            h3.u = *((const ushort4*)(uh1 + (size_t)entries[p+3] * 256 + l6 * 4));
            #pragma unroll
            for (int j = 0; j < 4; ++j) {
                A0[j] += (float)h0.h[j]; A1[j] += (float)h1.h[j];
                A2[j] += (float)h2.h[j]; A3[j] += (float)h3.h[j];
            }
        }
        for (; p < e_end; ++p) {
            H4 h0; h0.u = *((const ushort4*)(uh1 + (size_t)entries[p] * 256 + l6 * 4));
            #pragma unroll
            for (int j = 0; j < 4; ++j) A0[j] += (float)h0.h[j];
        }
        float r[4];
        #pragma unroll
        for (int j = 0; j < 4; ++j) r[j] = (A0[j] + A1[j]) + (A2[j] + A3[j]);
        int partner = (v < NN) ? v + NN : v - NN;
        float w0 = dvisf[v], w1 = dvisf[partner];
        float4 xv = (v < NN) ? x1[((size_t)(b * NN) + v) * 16 + f4i]
                             : x2[((size_t)(b * NN) + (v - NN)) * 16 + f4i];
        float4 xp = (partner < NN) ? x1[((size_t)(b * NN) + partner) * 16 + f4i]
                                   : x2[((size_t)(b * NN) + (partner - NN)) * 16 + f4i];
        r[0] += 0.25f * (xv.x * w0 + xp.x * w1);
        r[1] += 0.25f * (xv.y * w0 + xp.y * w1);
        r[2] += 0.25f * (xv.z * w0 + xp.z * w1);
        r[3] += 0.25f * (xv.w * w0 + xp.w * w1);
        int rloc = vl * 4 + b;
        #pragma unroll
        for (int j = 0; j < 4; ++j) xT[(c4 + j) * 33 + rloc] = r[j] * w0;
    }
    __syncthreads();
    int tr = tid >> 5, tc = tid & 31;
    int r0 = tr * 4, c0 = tc * 4;
    {                                     // gemm1 + relu -> zT
        float acc[4][4] = {{0.f}};
        #pragma unroll
        for (int k = 0; k < CC; ++k) {
            float xr0 = xT[k*33 + r0+0], xr1 = xT[k*33 + r0+1];
            float xr2 = xT[k*33 + r0+2], xr3 = xT[k*33 + r0+3];
            float4 w = *((const float4*)&wT[k * 132 + c0]);
            acc[0][0]+=xr0*w.x; acc[0][1]+=xr0*w.y; acc[0][2]+=xr0*w.z; acc[0][3]+=xr0*w.w;
            acc[1][0]+=xr1*w.x; acc[1][1]+=xr1*w.y; acc[1][2]+=xr1*w.z; acc[1][3]+=xr1*w.w;
            acc[2][0]+=xr2*w.x; acc[2][1]+=xr2*w.y; acc[2][2]+=xr2*w.z; acc[2][3]+=xr2*w.w;
            acc[3][0]+=xr3*w.x; acc[3][1]+=xr3*w.y; acc[3][2]+=xr3*w.z; acc[3][3]+=xr3*w.w;
        }
        #pragma unroll
        for (int i = 0; i < 4; ++i)
            #pragma unroll
            for (int j = 0; j < 4; ++j)
                zT[(c0 + j) * 33 + r0 + i] = fmaxf(acc[i][j], 0.f);
    }
    float acc2[4][4] = {{0.f}};
    for (int kc = 0; kc < 2; ++kc) {      // gemm2, z from LDS
        __syncthreads();                   // wT reads / zT writes done
        #pragma unroll
        for (int p = 0; p < 32; ++p) {     // stage W2T chunk
            int idx = p * 256 + tid;
            int k = idx >> 7, c = idx & 127;
            wT[k * 132 + c] = W2T[(size_t)(kc * 64 + k) * HD + c];
        }
        __syncthreads();
        #pragma unroll
        for (int k = 0; k < 64; ++k) {
            int kk = kc * 64 + k;
            float zr0 = zT[kk*33 + r0+0], zr1 = zT[kk*33 + r0+1];
            float zr2 = zT[kk*33 + r0+2], zr3 = zT[kk*33 + r0+3];
            float4 w = *((const float4*)&wT[k * 132 + c0]);
            acc2[0][0]+=zr0*w.x; acc2[0][1]+=zr0*w.y; acc2[0][2]+=zr0*w.z; acc2[0][3]+=zr0*w.w;
            acc2[1][0]+=zr1*w.x; acc2[1][1]+=zr1*w.y; acc2[1][2]+=zr1*w.z; acc2[1][3]+=zr1*w.w;
            acc2[2][0]+=zr2*w.x; acc2[2][1]+=zr2*w.y; acc2[2][2]+=zr2*w.z; acc2[2][3]+=zr2*w.w;
            acc2[3][0]+=zr3*w.x; acc2[3][1]+=zr3*w.y; acc2[3][2]+=zr3*w.z; acc2[3][3]+=zr3*w.w;
        }
    }
    #pragma unroll
    for (int i = 0; i < 4; ++i) {
        H4 ho;
        ho.h[0] = (h16)acc2[i][0]; ho.h[1] = (h16)acc2[i][1];
        ho.h[2] = (h16)acc2[i][2]; ho.h[3] = (h16)acc2[i][3];
        *((ushort4*)(yh + (size_t)(g0 + r0 + i) * HD + c0)) = ho.u;
    }
}

// ---------------------------------------------------------------------------
// 8) layer2 edge on fp16 y rows (1 KB). Grid 2NN x 128.
// ---------------------------------------------------------------------------
__global__ void k_edge2(const u16* __restrict__ yh, const float* __restrict__ dvisf,
                        const int* __restrict__ knn1, const int* __restrict__ knn2,
                        u16* __restrict__ uh2) {
    __shared__ int mem[19];
    __shared__ float wv[19];
    int blk = blockIdx.x;
    int t = threadIdx.x;            // 128; owns 4 halves of the 512-half row
    int off = t * 4;
    if (blk < NN) {
        if (t < 19) { int v = knn1[(size_t)blk * 19 + t]; mem[t] = v; wv[t] = dvisf[v]; }
        __syncthreads();
        float a0=0,a1=0,a2=0,a3=0;
        #pragma unroll
        for (int q = 0; q < 7; ++q) {
            float w = wv[q];
            H4 hv; hv.u = *((const ushort4*)(yh + (size_t)mem[q] * 512 + off));
            a0 += (float)hv.h[0]*w; a1 += (float)hv.h[1]*w;
            a2 += (float)hv.h[2]*w; a3 += (float)hv.h[3]*w;
        }
        { H4 ho; ho.h[0]=(h16)(a0*(1.f/49.f)); ho.h[1]=(h16)(a1*(1.f/49.f));
          ho.h[2]=(h16)(a2*(1.f/49.f)); ho.h[3]=(h16)(a3*(1.f/49.f));
          *((ushort4*)(uh2 + (size_t)blk * 512 + off)) = ho.u; }
        #pragma unroll
        for (int q = 7; q < 19; ++q) {
            float w = wv[q];
            H4 hv; hv.u = *((const ushort4*)(yh + (size_t)mem[q] * 512 + off));
            a0 += (float)hv.h[0]*w; a1 += (float)hv.h[1]*w;
            a2 += (float)hv.h[2]*w; a3 += (float)hv.h[3]*w;
        }
        { H4 ho; ho.h[0]=(h16)(a0*(1.f/361.f)); ho.h[1]=(h16)(a1*(1.f/361.f));
          ho.h[2]=(h16)(a2*(1.f/361.f)); ho.h[3]=(h16)(a3*(1.f/361.f));
          *((ushort4*)(uh2 + (size_t)(NN + blk) * 512 + off)) = ho.u; }
    } else {
        int i = blk - NN;
        if (t < 13) { int v = NN + knn2[(size_t)i * 13 + t]; mem[t] = v; wv[t] = dvisf[v]; }
        __syncthreads();
        float a0=0,a1=0,a2=0,a3=0;
        #pragma unroll
        for (int q = 0; q < 5; ++q) {
            float w = wv[q];
            H4 hv; hv.u = *((const ushort4*)(yh + (size_t)mem[q] * 512 + off));
            a0 += (float)hv.h[0]*w; a1 += (float)hv.h[1]*w;
            a2 += (float)hv.h[2]*w; a3 += (float)hv.h[3]*w;
        }
        { H4 ho; ho.h[0]=(h16)(a0*(1.f/25.f)); ho.h[1]=(h16)(a1*(1.f/25.f));
          ho.h[2]=(h16)(a2*(1.f/25.f)); ho.h[3]=(h16)(a3*(1.f/25.f));
          *((ushort4*)(uh2 + (size_t)(2 * NN + i) * 512 + off)) = ho.u; }
        #pragma unroll
        for (int q = 5; q < 13; ++q) {
            float w = wv[q];
            H4 hv; hv.u = *((const ushort4*)(yh + (size_t)mem[q] * 512 + off));
            a0 += (float)hv.h[0]*w; a1 += (float)hv.h[1]*w;
            a2 += (float)hv.h[2]*w; a3 += (float)hv.h[3]*w;
        }
        { H4 ho; ho.h[0]=(h16)(a0*(1.f/169.f)); ho.h[1]=(h16)(a1*(1.f/169.f));
          ho.h[2]=(h16)(a2*(1.f/169.f)); ho.h[3]=(h16)(a3*(1.f/169.f));
          *((ushort4*)(uh2 + (size_t)(3 * NN + i) * 512 + off)) = ho.u; }
    }
}

// ---------------------------------------------------------------------------
// 9) layer2 node -> final output (f32, batch-major, modality split). Grid 2N.
// ---------------------------------------------------------------------------
__global__ void k_node2(const u16* __restrict__ uh2, const u16* __restrict__ yh,
                        const float* __restrict__ dvisf,
                        const int* __restrict__ offs, const int* __restrict__ entries,
                        float* __restrict__ out) {
    int v = blockIdx.x;
    int t = threadIdx.x;            // 128
    int off = t * 4;
    int s = offs[v], e_end = offs[v + 1];
    float A0[4] = {0,0,0,0}, A1[4] = {0,0,0,0};
    float A2[4] = {0,0,0,0}, A3[4] = {0,0,0,0};
    int p = s;
    for (; p + 3 < e_end; p += 4) {
        H4 h0, h1, h2, h3;
        h0.u = *((const ushort4*)(uh2 + (size_t)entries[p+0] * 512 + off));
        h1.u = *((const ushort4*)(uh2 + (size_t)entries[p+1] * 512 + off));
        h2.u = *((const ushort4*)(uh2 + (size_t)entries[p+2] * 512 + off));
        h3.u = *((const ushort4*)(uh2 + (size_t)entries[p+3] * 512 + off));
        #pragma unroll
        for (int j = 0; j < 4; ++j) {
            A0[j] += (float)h0.h[j]; A1[j] += (float)h1.h[j];
            A2[j] += (float)h2.h[j]; A3[j] += (float)h3.h[j];
        }
    }
    for (; p < e_end; ++p) {
        H4 h0; h0.u = *((const ushort4*)(uh2 + (size_t)entries[p] * 512 + off));
        #pragma unroll
        for (int j = 0; j < 4; ++j) A0[j] += (float)h0.h[j];
    }
    float r[4];
    #pragma unroll
    for (int j = 0; j < 4; ++j) r[j] = (A0[j] + A1[j]) + (A2[j] + A3[j]);
    int partner = (v < NN) ? v + NN : v - NN;
    float w0 = dvisf[v], w1 = dvisf[partner];
    H4 yv, yp;
    yv.u = *((const ushort4*)(yh + (size_t)v * 512 + off));
    yp.u = *((const ushort4*)(yh + (size_t)partner * 512 + off));
    #pragma unroll
    for (int j = 0; j < 4; ++j) {
        r[j] += 0.25f * ((float)yv.h[j] * w0 + (float)yp.h[j] * w1);
        r[j] = fmaxf(r[j] * w0, 0.f);
    }
    int b = t >> 5, f4i = t & 31;
    size_t o4;
    if (v < NN) o4 = ((size_t)(b * NN + v)) * 32 + f4i;
    else        o4 = (size_t)BB * NN * 32 + ((size_t)(b * NN + (v - NN))) * 32 + f4i;
    ((float4*)out)[o4] = make_float4(r[0], r[1], r[2], r[3]);
}

// ---------------------------------------------------------------------------
extern "C" void kernel_launch(void* const* d_in, const int* in_sizes, int n_in,
                              void* d_out, int out_size, void* d_ws, size_t ws_size,
                              hipStream_t stream) {
    const float* f1 = (const float*)d_in[0];
    const float* f2 = (const float*)d_in[1];
    const float* W1 = (const float*)d_in[2];
    const float* W2 = (const float*)d_in[3];
    float* out = (float*)d_out;

    char* ws = (char*)d_ws;
    size_t off = 0;
    auto alloc = [&](size_t bytes) -> void* {
        void* p = ws + off;
        off = (off + bytes + 255) & ~(size_t)255;
        return p;
    };
    float*  g32T   = (float*)alloc((size_t)2 * CC * NN * 4);          // 1 MB
    double* gR64   = (double*)alloc((size_t)2 * NN * CC * 8);         // 2 MB
    u16*    simsbf = (u16*)alloc((size_t)2 * NN * NN * 2);            // 16 MB
    u16*    xh     = (u16*)alloc((size_t)TWO_N * BB * CC * 2);        // 2 MB
    u16*    uh1    = (u16*)alloc((size_t)4 * NN * BB * CC * 2);       // 4 MB
    u16*    yh     = (u16*)alloc((size_t)TWO_N * BB * HD * 2);        // 4 MB
    u16*    uh2    = (u16*)alloc((size_t)4 * NN * BB * HD * 2);       // 8 MB
    float*  W1T    = (float*)alloc((size_t)CC * HD * 4);
    float*  W2T    = (float*)alloc((size_t)HD * HD * 4);
    float*  dvisf  = (float*)alloc((size_t)TWO_N * 4);
    int*    knn1   = (int*)alloc((size_t)NN * 19 * 4);
    int*    knn2   = (int*)alloc((size_t)NN * 13 * 4);
    int*    DV     = (int*)alloc((size_t)TWO_N * 4);
    int*    offs   = (int*)alloc((size_t)(TWO_N + 1) * 4);
    int*    cursor = (int*)alloc((size_t)TWO_N * 4);
    int*    entries= (int*)alloc((size_t)(NN * 26 + NN * 18) * 4);

    // graph construction
    k_mean_norm<<<dim3(NN, 2), 64, 0, stream>>>(f1, f2, W1, W2, g32T, gR64,
                                                xh, W1T, W2T, DV);
    k_sims<<<dim3(32 * 32, 2), 256, 0, stream>>>(g32T, simsbf);
    k_selref<<<TWO_N / 8, 512, 0, stream>>>(simsbf, gR64, knn1, knn2, DV);
    k_scan<<<1, 64, 0, stream>>>(DV, offs, cursor, dvisf);
    k_fill<<<(NN * 19 + NN * 13 + 255) / 256, 256, 0, stream>>>(knn1, knn2, cursor, entries);

    // layer 1 (reordered: aggregate raw x-hat fp16, then fused gemms)
    k_edgeX<<<2 * NN, 64, 0, stream>>>(xh, dvisf, knn1, knn2, uh1);
    k_nodeGemm<<<(BB * TWO_N) / 32, 256, 0, stream>>>(uh1, f1, f2, dvisf, offs,
                                                      entries, W1T, W2T, yh);

    // layer 2
    k_edge2<<<2 * NN, 128, 0, stream>>>(yh, dvisf, knn1, knn2, uh2);
    k_node2<<<TWO_N, 128, 0, stream>>>(uh2, yh, dvisf, offs, entries, out);
}

// Round 5
// 188.824 us; speedup vs baseline: 4.1125x; 1.0596x over previous
//
#include <hip/hip_runtime.h>
#include <math.h>

// Problem constants
#define NN 2048      // nodes per modality
#define TWO_N 4096   // total nodes
#define BB 4         // batch
#define CC 64        // input feature dim
#define HD 128       // hidden dim
#define CANDCAP 32   // max candidates per row after margin filter

typedef unsigned short u16;
typedef _Float16 h16;
union H4 { ushort4 u; h16 h[4]; };

__device__ __forceinline__ u16 f2bf(float x) {   // RN-even f32 -> bf16
    unsigned u = __float_as_uint(x);
    u += 0x7FFFu + ((u >> 16) & 1u);
    return (u16)(u >> 16);
}

// ---------------------------------------------------------------------------
// 1) batch-mean + L2-normalize; also: DV zero, W1/W2 transpose, x -> fp16.
//    grid (NN, 2) x 64 threads.
// ---------------------------------------------------------------------------
__global__ void k_mean_norm(const float* __restrict__ f1, const float* __restrict__ f2,
                            const float* __restrict__ W1, const float* __restrict__ W2,
                            float* __restrict__ g32T, double* __restrict__ gR64,
                            u16* __restrict__ xh,
                            float* __restrict__ W1T, float* __restrict__ W2T,
                            int* __restrict__ DV) {
    int n = blockIdx.x;           // node
    int m = blockIdx.y;           // modality
    int c = threadIdx.x;          // 64 threads = 1 wave
    if (m == 0 && n < 64) DV[n * 64 + c] = 0;   // covers 0..4095
    if (m == 1) {
        if (n < 128) {            // W1T[k][o] from W1[o][k], 8192 elems
            int idx = n * 64 + c;
            W1T[(size_t)(idx & 63) * HD + (idx >> 6)] = W1[idx];
        } else if (n < 384) {     // W2T[k][o] from W2[o][k], 16384 elems
            int idx = (n - 128) * 64 + c;
            W2T[(size_t)(idx & 127) * HD + (idx >> 7)] = W2[idx];
        }
    }
    const float* f = m ? f2 : f1;
    float xv[BB];
    double s = 0.0;
    for (int b = 0; b < BB; ++b) {
        float v = f[((size_t)(b * NN) + n) * CC + c];
        xv[b] = v; s += (double)v;
    }
    h16* xrow = (h16*)(xh + ((size_t)(m * NN + n)) * (BB * CC));
    for (int b = 0; b < BB; ++b) xrow[b * CC + c] = (h16)xv[b];
    double mean = s * 0.25;
    double sq = mean * mean;
    for (int d = 32; d >= 1; d >>= 1) sq += __shfl_xor(sq, d);
    double norm = sqrt(sq);
    if (norm < 1e-12) norm = 1e-12;
    double g = mean / norm;
    g32T[((size_t)m * CC + c) * NN + n] = (float)g;
    gR64[((size_t)m * NN + n) * CC + c] = g;
}

// ---------------------------------------------------------------------------
// 2) f32 sims GEMM, symmetric (upper-tri tiles), bf16 store + mirror via LDS.
// ---------------------------------------------------------------------------
__global__ void __launch_bounds__(256)
k_sims(const float* __restrict__ g32T, u16* __restrict__ simsbf) {
    __shared__ float As[64 * 64];   // 16 KB
    __shared__ float Bs[64 * 64];   // 16 KB
    int m  = blockIdx.y;
    int bi = blockIdx.x >> 5, bj = blockIdx.x & 31;
    if (bi > bj) return;            // uniform exit before barriers
    int i0 = bi * 64, j0 = bj * 64;
    const float* g = g32T + (size_t)m * CC * NN;
    int tid = threadIdx.x;
    #pragma unroll
    for (int q = 0; q < 16; ++q) {
        int idx = q * 256 + tid;
        int k = idx >> 6, r = idx & 63;
        As[k * 64 + r] = g[(size_t)k * NN + i0 + r];
        Bs[k * 64 + r] = g[(size_t)k * NN + j0 + r];
    }
    __syncthreads();
    int tr = tid >> 4, tc = tid & 15;
    float acc[4][4] = {{0.f}};
    #pragma unroll
    for (int k = 0; k < CC; ++k) {
        float4 a = *((const float4*)&As[k * 64 + (tr << 2)]);
        float4 b = *((const float4*)&Bs[k * 64 + (tc << 2)]);
        acc[0][0] += a.x * b.x; acc[0][1] += a.x * b.y; acc[0][2] += a.x * b.z; acc[0][3] += a.x * b.w;
        acc[1][0] += a.y * b.x; acc[1][1] += a.y * b.y; acc[1][2] += a.y * b.z; acc[1][3] += a.y * b.w;
        acc[2][0] += a.z * b.x; acc[2][1] += a.z * b.y; acc[2][2] += a.z * b.z; acc[2][3] += a.z * b.w;
        acc[3][0] += a.w * b.x; acc[3][1] += a.w * b.y; acc[3][2] += a.w * b.z; acc[3][3] += a.w * b.w;
    }
    __syncthreads();                // As free -> reuse as bf16 bounce [64][66]
    u16* Cs = (u16*)As;
    u16* srow = simsbf + (size_t)m * NN * NN;
    #pragma unroll
    for (int x = 0; x < 4; ++x) {
        ushort4 vd;
        vd.x = f2bf(acc[x][0]); vd.y = f2bf(acc[x][1]);
        vd.z = f2bf(acc[x][2]); vd.w = f2bf(acc[x][3]);
        *((ushort4*)&srow[(size_t)(i0 + (tr << 2) + x) * NN + j0 + (tc << 2)]) = vd;
        int cr = ((tr << 2) + x) * 66 + (tc << 2);
        Cs[cr + 0] = vd.x; Cs[cr + 1] = vd.y; Cs[cr + 2] = vd.z; Cs[cr + 3] = vd.w;
    }
    __syncthreads();
    #pragma unroll
    for (int q = 0; q < 4; ++q) {
        int idx = q * 256 + tid;
        int cc = idx >> 4, rr4 = (idx & 15) << 2;
        ushort4 vd;
        vd.x = Cs[(rr4 + 0) * 66 + cc];
        vd.y = Cs[(rr4 + 1) * 66 + cc];
        vd.z = Cs[(rr4 + 2) * 66 + cc];
        vd.w = Cs[(rr4 + 3) * 66 + cc];
        *((ushort4*)&srow[(size_t)(j0 + cc) * NN + i0 + rr4]) = vd;
    }
}

// ---------------------------------------------------------------------------
// 3) select (bf16, margin 6e-3) + f64-exact refine. Proven R2-R4.
// ---------------------------------------------------------------------------
__global__ void __launch_bounds__(512)
k_selref(const u16* __restrict__ simsbf, const double* __restrict__ gR64,
         int* __restrict__ knn1, int* __restrict__ knn2, int* __restrict__ DV) {
    __shared__ int    candL[8][CANDCAP];
    __shared__ double dotsL[8][CANDCAP];
    int wave = threadIdx.x >> 6, lane = threadIdx.x & 63;
    int row = blockIdx.x * 8 + wave;    // 0..4095
    int m = row >> 11, i = row & 2047;
    int K = m ? 13 : 19;
    const u16* s = simsbf + (size_t)m * NN * NN + (size_t)i * NN;
    float sv[32];
    #pragma unroll
    for (int q = 0; q < 4; ++q) {
        uint4 w = *((const uint4*)(s + q * 512 + (lane << 3)));
        sv[q*8+0] = __uint_as_float(w.x << 16);
        sv[q*8+1] = __uint_as_float(w.x & 0xFFFF0000u);
        sv[q*8+2] = __uint_as_float(w.y << 16);
        sv[q*8+3] = __uint_as_float(w.y & 0xFFFF0000u);
        sv[q*8+4] = __uint_as_float(w.z << 16);
        sv[q*8+5] = __uint_as_float(w.z & 0xFFFF0000u);
        sv[q*8+6] = __uint_as_float(w.w << 16);
        sv[q*8+7] = __uint_as_float(w.w & 0xFFFF0000u);
    }
    float lo = -1.01f, hi = 1.01f;
    for (int it = 0; it < 12; ++it) {
        float t = 0.5f * (lo + hi);
        int c = 0;
        #pragma unroll
        for (int r = 0; r < 32; ++r)
            c += __popcll(__ballot(sv[r] >= t));
        if (c >= K) lo = t; else hi = t;   // wave-uniform
    }
    float thr = lo - 6e-3f;
    unsigned long long ltmask = (lane == 0) ? 0ull : ((~0ull) >> (64 - lane));
    int base = 0;
    #pragma unroll
    for (int r = 0; r < 32; ++r) {
        int j = ((r >> 3) << 9) + (lane << 3) + (r & 7);
        bool p = sv[r] >= thr;
        unsigned long long mk = __ballot(p);
        int ofs = base + __popcll(mk & ltmask);
        if (p && ofs < CANDCAP) candL[wave][ofs] = j;
        base += __popcll(mk);
    }
    int cnt = (base < CANDCAP) ? base : CANDCAP;
    __syncthreads();
    const double* gm = gR64 + (size_t)m * NN * CC;
    double qc = gm[(size_t)i * CC + lane];
    int t4 = 0;
    for (; t4 + 3 < cnt; t4 += 4) {       // 4 independent reduce chains
        int j0c = candL[wave][t4 + 0], j1c = candL[wave][t4 + 1];
        int j2c = candL[wave][t4 + 2], j3c = candL[wave][t4 + 3];
        double p0 = qc * gm[(size_t)j0c * CC + lane];
        double p1 = qc * gm[(size_t)j1c * CC + lane];
        double p2 = qc * gm[(size_t)j2c * CC + lane];
        double p3 = qc * gm[(size_t)j3c * CC + lane];
        #pragma unroll
        for (int d = 32; d >= 1; d >>= 1) {
            p0 += __shfl_xor(p0, d); p1 += __shfl_xor(p1, d);
            p2 += __shfl_xor(p2, d); p3 += __shfl_xor(p3, d);
        }
        if (lane == 0) {
            dotsL[wave][t4 + 0] = p0; dotsL[wave][t4 + 1] = p1;
            dotsL[wave][t4 + 2] = p2; dotsL[wave][t4 + 3] = p3;
        }
    }
    for (; t4 < cnt; ++t4) {
        int j = candL[wave][t4];
        double p = qc * gm[(size_t)j * CC + lane];
        #pragma unroll
        for (int d = 32; d >= 1; d >>= 1) p += __shfl_xor(p, d);
        if (lane == 0) dotsL[wave][t4] = p;
    }
    __syncthreads();
    int* knn = m ? knn2 : knn1;
    if (lane < cnt) {
        double vt = dotsL[wave][lane]; int jt = candL[wave][lane];
        int rank = 0;
        for (int s2 = 0; s2 < cnt; ++s2) {
            double vs = dotsL[wave][s2]; int js = candL[wave][s2];
            if (vs > vt || (vs == vt && js < jt)) ++rank;
        }
        if (rank < K) {
            knn[(size_t)i * K + rank] = jt;
            int w = (rank < (m ? 5 : 7)) ? 2 : 1;
            atomicAdd(&DV[m ? NN + jt : jt], w);
        }
    }
}

// ---------------------------------------------------------------------------
// 4) exclusive scan -> CSR offsets; dvisf = 1/sqrt(DV+1).
// ---------------------------------------------------------------------------
__global__ void k_scan(const int* __restrict__ DV, int* __restrict__ offs,
                       int* __restrict__ cursor, float* __restrict__ dvisf) {
    int lane = threadIdx.x;      // 64
    int base = lane * 64;
    int s = 0;
    for (int q = 0; q < 64; ++q) s += DV[base + q];
    int x = s;
    for (int d = 1; d < 64; d <<= 1) {
        int y = __shfl_up(x, d);
        if (lane >= d) x += y;
    }
    int run = x - s;
    for (int q = 0; q < 64; ++q) {
        int v = base + q;
        offs[v] = run; cursor[v] = run;
        dvisf[v] = (float)(1.0 / sqrt((double)(DV[v] + 1)));
        run += DV[v];
    }
    if (lane == 63) offs[TWO_N] = run;
}

// ---------------------------------------------------------------------------
// 5) fill CSR transpose.
// ---------------------------------------------------------------------------
__global__ void k_fill(const int* __restrict__ knn1, const int* __restrict__ knn2,
                       int* __restrict__ cursor, int* __restrict__ entries) {
    int id = blockIdx.x * blockDim.x + threadIdx.x;
    const int M1 = NN * 19, M2 = NN * 13;
    if (id < M1) {
        int i = id / 19, t = id % 19;
        int v = knn1[id];
        int p = atomicAdd(&cursor[v], 1); entries[p] = NN + i;
        if (t < 7) { int p2 = atomicAdd(&cursor[v], 1); entries[p2] = i; }
    } else if (id < M1 + M2) {
        int id2 = id - M1;
        int i = id2 / 13, t = id2 % 13;
        int v = NN + knn2[id2];
        int p = atomicAdd(&cursor[v], 1); entries[p] = 3 * NN + i;
        if (t < 5) { int p2 = atomicAdd(&cursor[v], 1); entries[p2] = 2 * NN + i; }
    }
}

// ---------------------------------------------------------------------------
// 6) layer1 edge on fp16 x-hat rows (512 B). Grid 2NN x 64; shfl members.
// ---------------------------------------------------------------------------
__global__ void k_edgeX(const u16* __restrict__ xh, const float* __restrict__ dvisf,
                        const int* __restrict__ knn1, const int* __restrict__ knn2,
                        u16* __restrict__ uh1) {
    int blk = blockIdx.x;
    int t = threadIdx.x;            // 64; owns 4 halves of the 256-half row
    int off = t * 4;
    if (blk < NN) {                 // m1 pair: k6 (7) + k18 (19)
        int mv = 0; float wv = 0.f;
        if (t < 19) { mv = knn1[(size_t)blk * 19 + t]; wv = dvisf[mv]; }
        float a0=0,a1=0,a2=0,a3=0;
        #pragma unroll
        for (int q = 0; q < 7; ++q) {
            int mq = __shfl(mv, q); float wq = __shfl(wv, q);
            H4 hv; hv.u = *((const ushort4*)(xh + (size_t)mq * 256 + off));
            a0 += (float)hv.h[0]*wq; a1 += (float)hv.h[1]*wq;
            a2 += (float)hv.h[2]*wq; a3 += (float)hv.h[3]*wq;
        }
        { H4 ho; ho.h[0]=(h16)(a0*(1.f/49.f)); ho.h[1]=(h16)(a1*(1.f/49.f));
          ho.h[2]=(h16)(a2*(1.f/49.f)); ho.h[3]=(h16)(a3*(1.f/49.f));
          *((ushort4*)(uh1 + (size_t)blk * 256 + off)) = ho.u; }
        #pragma unroll
        for (int q = 7; q < 19; ++q) {
            int mq = __shfl(mv, q); float wq = __shfl(wv, q);
            H4 hv; hv.u = *((const ushort4*)(xh + (size_t)mq * 256 + off));
            a0 += (float)hv.h[0]*wq; a1 += (float)hv.h[1]*wq;
            a2 += (float)hv.h[2]*wq; a3 += (float)hv.h[3]*wq;
        }
        { H4 ho; ho.h[0]=(h16)(a0*(1.f/361.f)); ho.h[1]=(h16)(a1*(1.f/361.f));
          ho.h[2]=(h16)(a2*(1.f/361.f)); ho.h[3]=(h16)(a3*(1.f/361.f));
          *((ushort4*)(uh1 + (size_t)(NN + blk) * 256 + off)) = ho.u; }
    } else {                        // m2 pair: k4 (5) + k12 (13)
        int i = blk - NN;
        int mv = 0; float wv = 0.f;
        if (t < 13) { mv = knn2[(size_t)i * 13 + t]; wv = dvisf[NN + mv]; }
        float a0=0,a1=0,a2=0,a3=0;
        #pragma unroll
        for (int q = 0; q < 5; ++q) {
            int mq = __shfl(mv, q); float wq = __shfl(wv, q);
            H4 hv; hv.u = *((const ushort4*)(xh + (size_t)(NN + mq) * 256 + off));
            a0 += (float)hv.h[0]*wq; a1 += (float)hv.h[1]*wq;
            a2 += (float)hv.h[2]*wq; a3 += (float)hv.h[3]*wq;
        }
        { H4 ho; ho.h[0]=(h16)(a0*(1.f/25.f)); ho.h[1]=(h16)(a1*(1.f/25.f));
          ho.h[2]=(h16)(a2*(1.f/25.f)); ho.h[3]=(h16)(a3*(1.f/25.f));
          *((ushort4*)(uh1 + (size_t)(2 * NN + i) * 256 + off)) = ho.u; }
        #pragma unroll
        for (int q = 5; q < 13; ++q) {
            int mq = __shfl(mv, q); float wq = __shfl(wv, q);
            H4 hv; hv.u = *((const ushort4*)(xh + (size_t)(NN + mq) * 256 + off));
            a0 += (float)hv.h[0]*wq; a1 += (float)hv.h[1]*wq;
            a2 += (float)hv.h[2]*wq; a3 += (float)hv.h[3]*wq;
        }
        { H4 ho; ho.h[0]=(h16)(a0*(1.f/169.f)); ho.h[1]=(h16)(a1*(1.f/169.f));
          ho.h[2]=(h16)(a2*(1.f/169.f)); ho.h[3]=(h16)(a3*(1.f/169.f));
          *((ushort4*)(uh1 + (size_t)(3 * NN + i) * 256 + off)) = ho.u; }
    }
}

// ---------------------------------------------------------------------------
// 7a) layer1 node gather ONLY (split from gemm: gather is latency-bound and
//     needs occupancy; R4's fused kernel ran it at 2 blocks/CU -> 44 us).
//     Grid 2N x 64, no LDS -> high occupancy, 4-deep MLP.
//     Writes aggxh fp16 (v-major, 256 halves/row), inter-edge + w0 included.
// ---------------------------------------------------------------------------
__global__ void k_node1(const u16* __restrict__ uh1,
                        const float* __restrict__ f1, const float* __restrict__ f2,
                        const float* __restrict__ dvisf,
                        const int* __restrict__ offs, const int* __restrict__ entries,
                        u16* __restrict__ aggxh) {
    int v = blockIdx.x;
    int l6 = threadIdx.x;           // 64
    int b = l6 >> 4, f4i = l6 & 15;
    int s = offs[v], e_end = offs[v + 1];
    float A0[4] = {0,0,0,0}, A1[4] = {0,0,0,0};
    float A2[4] = {0,0,0,0}, A3[4] = {0,0,0,0};
    int p = s;
    for (; p + 3 < e_end; p += 4) {
        H4 h0, h1, h2, h3;
        h0.u = *((const ushort4*)(uh1 + (size_t)entries[p+0] * 256 + l6 * 4));
        h1.u = *((const ushort4*)(uh1 + (size_t)entries[p+1] * 256 + l6 * 4));
        h2.u = *((const ushort4*)(uh1 + (size_t)entries[p+2] * 256 + l6 * 4));
        h3.u = *((const ushort4*)(uh1 + (size_t)entries[p+3] * 256 + l6 * 4));
        #pragma unroll
        for (int j = 0; j < 4; ++j) {
            A0[j] += (float)h0.h[j]; A1[j] += (float)h1.h[j];
            A2[j] += (float)h2.h[j]; A3[j] += (float)h3.h[j];
        }
    }
    for (; p < e_end; ++p) {
        H4 h0; h0.u = *((const ushort4*)(uh1 + (size_t)entries[p] * 256 + l6 * 4));
        #pragma unroll
        for (int j = 0; j < 4; ++j) A0[j] += (float)h0.h[j];
    }
    float r[4];
    #pragma unroll
    for (int j = 0; j < 4; ++j) r[j] = (A0[j] + A1[j]) + (A2[j] + A3[j]);
    int partner = (v < NN) ? v + NN : v - NN;
    float w0 = dvisf[v], w1 = dvisf[partner];
    const float4* x1 = (const float4*)f1;
    const float4* x2 = (const float4*)f2;
    float4 xv = (v < NN) ? x1[((size_t)(b * NN) + v) * 16 + f4i]
                         : x2[((size_t)(b * NN) + (v - NN)) * 16 + f4i];
    float4 xp = (partner < NN) ? x1[((size_t)(b * NN) + partner) * 16 + f4i]
                               : x2[((size_t)(b * NN) + (partner - NN)) * 16 + f4i];
    r[0] += 0.25f * (xv.x * w0 + xp.x * w1);
    r[1] += 0.25f * (xv.y * w0 + xp.y * w1);
    r[2] += 0.25f * (xv.z * w0 + xp.z * w1);
    r[3] += 0.25f * (xv.w * w0 + xp.w * w1);
    H4 ho;
    #pragma unroll
    for (int j = 0; j < 4; ++j) ho.h[j] = (h16)(r[j] * w0);
    *((ushort4*)(aggxh + (size_t)v * 256 + l6 * 4)) = ho.u;
}

// ---------------------------------------------------------------------------
// 7b) FUSED gemm1(relu)+gemm2 from aggxh, z in LDS. 512 blocks x 256 thr.
//     Pure compute at 2 blocks/CU (no latency-bound phase inside anymore).
// ---------------------------------------------------------------------------
__global__ void __launch_bounds__(256)
k_gemm12(const u16* __restrict__ aggxh,
         const float* __restrict__ W1T, const float* __restrict__ W2T,
         u16* __restrict__ yh) {
    __shared__ float wT[64 * 132];   // 33.8 KB
    __shared__ float xT[64 * 33];    //  8.4 KB
    __shared__ float zT[128 * 33];   // 16.9 KB
    int tid = threadIdx.x;
    int bid = blockIdx.x;            // 0..511
    int v0 = bid * 8, g0 = bid * 32;
    #pragma unroll
    for (int p = 0; p < 32; ++p) {   // stage W1T
        int idx = p * 256 + tid;
        wT[(idx >> 7) * 132 + (idx & 127)] = W1T[idx];
    }
    #pragma unroll
    for (int it = 0; it < 2; ++it) { // stage aggx: 512 items = 8 nodes x 64 lanes
        int item = it * 256 + tid;
        int vl = item >> 6, l6 = item & 63;
        int b = l6 >> 4, c4 = (l6 & 15) << 2;
        H4 hv; hv.u = *((const ushort4*)(aggxh + (size_t)(v0 + vl) * 256 + l6 * 4));
        int rloc = vl * 4 + b;
        #pragma unroll
        for (int j = 0; j < 4; ++j) xT[(c4 + j) * 33 + rloc] = (float)hv.h[j];
    }
    __syncthreads();
    int tr = tid >> 5, tc = tid & 31;
    int r0 = tr * 4, c0 = tc * 4;
    {                                     // gemm1 + relu -> zT
        float acc[4][4] = {{0.f}};
        #pragma unroll
        for (int k = 0; k < CC; ++k) {
            float xr0 = xT[k*33 + r0+0], xr1 = xT[k*33 + r0+1];
            float xr2 = xT[k*33 + r0+2], xr3 = xT[k*33 + r0+3];
            float4 w = *((const float4*)&wT[k * 132 + c0]);
            acc[0][0]+=xr0*w.x; acc[0][1]+=xr0*w.y; acc[0][2]+=xr0*w.z; acc[0][3]+=xr0*w.w;
            acc[1][0]+=xr1*w.x; acc[1][1]+=xr1*w.y; acc[1][2]+=xr1*w.z; acc[1][3]+=xr1*w.w;
            acc[2][0]+=xr2*w.x; acc[2][1]+=xr2*w.y; acc[2][2]+=xr2*w.z; acc[2][3]+=xr2*w.w;
            acc[3][0]+=xr3*w.x; acc[3][1]+=xr3*w.y; acc[3][2]+=xr3*w.z; acc[3][3]+=xr3*w.w;
        }
        #pragma unroll
        for (int i = 0; i < 4; ++i)
            #pragma unroll
            for (int j = 0; j < 4; ++j)
                zT[(c0 + j) * 33 + r0 + i] = fmaxf(acc[i][j], 0.f);
    }
    float acc2[4][4] = {{0.f}};
    for (int kc = 0; kc < 2; ++kc) {      // gemm2, z from LDS
        __syncthreads();                   // wT reads / zT writes done
        #pragma unroll
        for (int p = 0; p < 32; ++p) {     // stage W2T chunk
            int idx = p * 256 + tid;
            int k = idx >> 7, c = idx & 127;
            wT[k * 132 + c] = W2T[(size_t)(kc * 64 + k) * HD + c];
        }
        __syncthreads();
        #pragma unroll
        for (int k = 0; k < 64; ++k) {
            int kk = kc * 64 + k;
            float zr0 = zT[kk*33 + r0+0], zr1 = zT[kk*33 + r0+1];
            float zr2 = zT[kk*33 + r0+2], zr3 = zT[kk*33 + r0+3];
            float4 w = *((const float4*)&wT[k * 132 + c0]);
            acc2[0][0]+=zr0*w.x; acc2[0][1]+=zr0*w.y; acc2[0][2]+=zr0*w.z; acc2[0][3]+=zr0*w.w;
            acc2[1][0]+=zr1*w.x; acc2[1][1]+=zr1*w.y; acc2[1][2]+=zr1*w.z; acc2[1][3]+=zr1*w.w;
            acc2[2][0]+=zr2*w.x; acc2[2][1]+=zr2*w.y; acc2[2][2]+=zr2*w.z; acc2[2][3]+=zr2*w.w;
            acc2[3][0]+=zr3*w.x; acc2[3][1]+=zr3*w.y; acc2[3][2]+=zr3*w.z; acc2[3][3]+=zr3*w.w;
        }
    }
    #pragma unroll
    for (int i = 0; i < 4; ++i) {
        H4 ho;
        ho.h[0] = (h16)acc2[i][0]; ho.h[1] = (h16)acc2[i][1];
        ho.h[2] = (h16)acc2[i][2]; ho.h[3] = (h16)acc2[i][3];
        *((ushort4*)(yh + (size_t)(g0 + r0 + i) * HD + c0)) = ho.u;
    }
}

// ---------------------------------------------------------------------------
// 8) layer2 edge on fp16 y rows (1 KB). Grid 2NN x 128.
// ---------------------------------------------------------------------------
__global__ void k_edge2(const u16* __restrict__ yh, const float* __restrict__ dvisf,
                        const int* __restrict__ knn1, const int* __restrict__ knn2,
                        u16* __restrict__ uh2) {
    __shared__ int mem[19];
    __shared__ float wv[19];
    int blk = blockIdx.x;
    int t = threadIdx.x;            // 128; owns 4 halves of the 512-half row
    int off = t * 4;
    if (blk < NN) {
        if (t < 19) { int v = knn1[(size_t)blk * 19 + t]; mem[t] = v; wv[t] = dvisf[v]; }
        __syncthreads();
        float a0=0,a1=0,a2=0,a3=0;
        #pragma unroll
        for (int q = 0; q < 7; ++q) {
            float w = wv[q];
            H4 hv; hv.u = *((const ushort4*)(yh + (size_t)mem[q] * 512 + off));
            a0 += (float)hv.h[0]*w; a1 += (float)hv.h[1]*w;
            a2 += (float)hv.h[2]*w; a3 += (float)hv.h[3]*w;
        }
        { H4 ho; ho.h[0]=(h16)(a0*(1.f/49.f)); ho.h[1]=(h16)(a1*(1.f/49.f));
          ho.h[2]=(h16)(a2*(1.f/49.f)); ho.h[3]=(h16)(a3*(1.f/49.f));
          *((ushort4*)(uh2 + (size_t)blk * 512 + off)) = ho.u; }
        #pragma unroll
        for (int q = 7; q < 19; ++q) {
            float w = wv[q];
            H4 hv; hv.u = *((const ushort4*)(yh + (size_t)mem[q] * 512 + off));
            a0 += (float)hv.h[0]*w; a1 += (float)hv.h[1]*w;
            a2 += (float)hv.h[2]*w; a3 += (float)hv.h[3]*w;
        }
        { H4 ho; ho.h[0]=(h16)(a0*(1.f/361.f)); ho.h[1]=(h16)(a1*(1.f/361.f));
          ho.h[2]=(h16)(a2*(1.f/361.f)); ho.h[3]=(h16)(a3*(1.f/361.f));
          *((ushort4*)(uh2 + (size_t)(NN + blk) * 512 + off)) = ho.u; }
    } else {
        int i = blk - NN;
        if (t < 13) { int v = NN + knn2[(size_t)i * 13 + t]; mem[t] = v; wv[t] = dvisf[v]; }
        __syncthreads();
        float a0=0,a1=0,a2=0,a3=0;
        #pragma unroll
        for (int q = 0; q < 5; ++q) {
            float w = wv[q];
            H4 hv; hv.u = *((const ushort4*)(yh + (size_t)mem[q] * 512 + off));
            a0 += (float)hv.h[0]*w; a1 += (float)hv.h[1]*w;
            a2 += (float)hv.h[2]*w; a3 += (float)hv.h[3]*w;
        }
        { H4 ho; ho.h[0]=(h16)(a0*(1.f/25.f)); ho.h[1]=(h16)(a1*(1.f/25.f));
          ho.h[2]=(h16)(a2*(1.f/25.f)); ho.h[3]=(h16)(a3*(1.f/25.f));
          *((ushort4*)(uh2 + (size_t)(2 * NN + i) * 512 + off)) = ho.u; }
        #pragma unroll
        for (int q = 5; q < 13; ++q) {
            float w = wv[q];
            H4 hv; hv.u = *((const ushort4*)(yh + (size_t)mem[q] * 512 + off));
            a0 += (float)hv.h[0]*w; a1 += (float)hv.h[1]*w;
            a2 += (float)hv.h[2]*w; a3 += (float)hv.h[3]*w;
        }
        { H4 ho; ho.h[0]=(h16)(a0*(1.f/169.f)); ho.h[1]=(h16)(a1*(1.f/169.f));
          ho.h[2]=(h16)(a2*(1.f/169.f)); ho.h[3]=(h16)(a3*(1.f/169.f));
          *((ushort4*)(uh2 + (size_t)(3 * NN + i) * 512 + off)) = ho.u; }
    }
}

// ---------------------------------------------------------------------------
// 9) layer2 node -> final output (f32, batch-major, modality split). Grid 2N.
// ---------------------------------------------------------------------------
__global__ void k_node2(const u16* __restrict__ uh2, const u16* __restrict__ yh,
                        const float* __restrict__ dvisf,
                        const int* __restrict__ offs, const int* __restrict__ entries,
                        float* __restrict__ out) {
    int v = blockIdx.x;
    int t = threadIdx.x;            // 128
    int off = t * 4;
    int s = offs[v], e_end = offs[v + 1];
    float A0[4] = {0,0,0,0}, A1[4] = {0,0,0,0};
    float A2[4] = {0,0,0,0}, A3[4] = {0,0,0,0};
    int p = s;
    for (; p + 3 < e_end; p += 4) {
        H4 h0, h1, h2, h3;
        h0.u = *((const ushort4*)(uh2 + (size_t)entries[p+0] * 512 + off));
        h1.u = *((const ushort4*)(uh2 + (size_t)entries[p+1] * 512 + off));
        h2.u = *((const ushort4*)(uh2 + (size_t)entries[p+2] * 512 + off));
        h3.u = *((const ushort4*)(uh2 + (size_t)entries[p+3] * 512 + off));
        #pragma unroll
        for (int j = 0; j < 4; ++j) {
            A0[j] += (float)h0.h[j]; A1[j] += (float)h1.h[j];
            A2[j] += (float)h2.h[j]; A3[j] += (float)h3.h[j];
        }
    }
    for (; p < e_end; ++p) {
        H4 h0; h0.u = *((const ushort4*)(uh2 + (size_t)entries[p] * 512 + off));
        #pragma unroll
        for (int j = 0; j < 4; ++j) A0[j] += (float)h0.h[j];
    }
    float r[4];
    #pragma unroll
    for (int j = 0; j < 4; ++j) r[j] = (A0[j] + A1[j]) + (A2[j] + A3[j]);
    int partner = (v < NN) ? v + NN : v - NN;
    float w0 = dvisf[v], w1 = dvisf[partner];
    H4 yv, yp;
    yv.u = *((const ushort4*)(yh + (size_t)v * 512 + off));
    yp.u = *((const ushort4*)(yh + (size_t)partner * 512 + off));
    #pragma unroll
    for (int j = 0; j < 4; ++j) {
        r[j] += 0.25f * ((float)yv.h[j] * w0 + (float)yp.h[j] * w1);
        r[j] = fmaxf(r[j] * w0, 0.f);
    }
    int b = t >> 5, f4i = t & 31;
    size_t o4;
    if (v < NN) o4 = ((size_t)(b * NN + v)) * 32 + f4i;
    else        o4 = (size_t)BB * NN * 32 + ((size_t)(b * NN + (v - NN))) * 32 + f4i;
    ((float4*)out)[o4] = make_float4(r[0], r[1], r[2], r[3]);
}

// ---------------------------------------------------------------------------
extern "C" void kernel_launch(void* const* d_in, const int* in_sizes, int n_in,
                              void* d_out, int out_size, void* d_ws, size_t ws_size,
                              hipStream_t stream) {
    const float* f1 = (const float*)d_in[0];
    const float* f2 = (const float*)d_in[1];
    const float* W1 = (const float*)d_in[2];
    const float* W2 = (const float*)d_in[3];
    float* out = (float*)d_out;

    char* ws = (char*)d_ws;
    size_t off = 0;
    auto alloc = [&](size_t bytes) -> void* {
        void* p = ws + off;
        off = (off + bytes + 255) & ~(size_t)255;
        return p;
    };
    float*  g32T   = (float*)alloc((size_t)2 * CC * NN * 4);          // 1 MB
    double* gR64   = (double*)alloc((size_t)2 * NN * CC * 8);         // 2 MB
    u16*    simsbf = (u16*)alloc((size_t)2 * NN * NN * 2);            // 16 MB
    u16*    xh     = (u16*)alloc((size_t)TWO_N * BB * CC * 2);        // 2 MB
    u16*    uh1    = (u16*)alloc((size_t)4 * NN * BB * CC * 2);       // 4 MB
    u16*    aggxh  = (u16*)alloc((size_t)TWO_N * BB * CC * 2);        // 2 MB
    u16*    yh     = (u16*)alloc((size_t)TWO_N * BB * HD * 2);        // 4 MB
    u16*    uh2    = (u16*)alloc((size_t)4 * NN * BB * HD * 2);       // 8 MB
    float*  W1T    = (float*)alloc((size_t)CC * HD * 4);
    float*  W2T    = (float*)alloc((size_t)HD * HD * 4);
    float*  dvisf  = (float*)alloc((size_t)TWO_N * 4);
    int*    knn1   = (int*)alloc((size_t)NN * 19 * 4);
    int*    knn2   = (int*)alloc((size_t)NN * 13 * 4);
    int*    DV     = (int*)alloc((size_t)TWO_N * 4);
    int*    offs   = (int*)alloc((size_t)(TWO_N + 1) * 4);
    int*    cursor = (int*)alloc((size_t)TWO_N * 4);
    int*    entries= (int*)alloc((size_t)(NN * 26 + NN * 18) * 4);

    // graph construction
    k_mean_norm<<<dim3(NN, 2), 64, 0, stream>>>(f1, f2, W1, W2, g32T, gR64,
                                                xh, W1T, W2T, DV);
    k_sims<<<dim3(32 * 32, 2), 256, 0, stream>>>(g32T, simsbf);
    k_selref<<<TWO_N / 8, 512, 0, stream>>>(simsbf, gR64, knn1, knn2, DV);
    k_scan<<<1, 64, 0, stream>>>(DV, offs, cursor, dvisf);
    k_fill<<<(NN * 19 + NN * 13 + 255) / 256, 256, 0, stream>>>(knn1, knn2, cursor, entries);

    // layer 1 (reordered: aggregate raw x-hat fp16, then fused gemms)
    k_edgeX<<<2 * NN, 64, 0, stream>>>(xh, dvisf, knn1, knn2, uh1);
    k_node1<<<TWO_N, 64, 0, stream>>>(uh1, f1, f2, dvisf, offs, entries, aggxh);
    k_gemm12<<<(BB * TWO_N) / 32, 256, 0, stream>>>(aggxh, W1T, W2T, yh);

    // layer 2
    k_edge2<<<2 * NN, 128, 0, stream>>>(yh, dvisf, knn1, knn2, uh2);
    k_node2<<<TWO_N, 128, 0, stream>>>(uh2, yh, dvisf, offs, entries, out);
}